// Round 8
// baseline (404.404 us; speedup 1.0000x reference)
//
#include <hip/hip_runtime.h>
#include <hip/hip_bf16.h>

#define N_TOK 4096
#define D_DIM 512
#define E_NUM 8
#define H_DIM 2048
#define RB_NUM 256   // router blocks (16 tokens each)
#define TP_NUM 8704  // transpose tiles (64x32): 4096 wg + 4096 wu + 512 wd

typedef __attribute__((ext_vector_type(8))) short short8;
typedef __attribute__((ext_vector_type(4))) float f32x4;

__device__ inline short f2bs(float f) {
  __hip_bfloat16 h = __float2bfloat16(f);
  return *reinterpret_cast<short*>(&h);
}

// async global->LDS, 16 B per lane; lds dest is wave-uniform base + lane*16
__device__ inline void llds16(const short* g, short* l) {
  __builtin_amdgcn_global_load_lds(
      (const __attribute__((address_space(1))) void*)g,
      (__attribute__((address_space(3))) void*)l, 16, 0, 0);
}

// ---------- fused prep+router ----------
// blocks [0,256): router (16 tokens each, 16 lanes/token)
// blocks [256, 256+8704): 64r x 32c transpose tiles (wg/wu/wd)
// load phase: float4 (16 B/lane, 2 rounds); pack phase: round-0 proven scalar
__global__ void __launch_bounds__(256) prep_router_kernel(
    const float* __restrict__ wg, const float* __restrict__ wu,
    const float* __restrict__ wd, const float* __restrict__ x,
    const float* __restrict__ wr, short* __restrict__ wgb,
    short* __restrict__ wub, short* __restrict__ wdb, short* __restrict__ xb,
    int* __restrict__ cnt_blk, int* __restrict__ tok_bkt,
    float* __restrict__ p_bkt, float* __restrict__ psum_blk) {
  int u = blockIdx.x;
  int tid = threadIdx.x;

  if (u >= RB_NUM) {
    // ---- 64r x 32c transpose-convert, int-packed bf16 writes ----
    __shared__ float tbuf[64][33];
    int v = u - RB_NUM;
    const float* in;
    short* op;
    int R, C, c0, r0;
    if (v < 8192) {
      in = (v < 4096) ? wg : wu;
      op = (v < 4096) ? wgb : wub;
      int w = v & 4095;
      R = D_DIM; C = E_NUM * H_DIM;
      c0 = (w & 511) * 32; r0 = (w >> 9) * 64;
    } else {
      in = wd; op = wdb;
      int w = v - 8192;
      R = H_DIM; C = D_DIM;
      c0 = (w & 15) * 32; r0 = (w >> 4) * 64;
    }
    // load phase: float4 per lane; covers rows 0..63, cols 0..31
    int cx = tid & 7, ry = tid >> 3;  // cx: float4-col 0..7, ry: row 0..31
#pragma unroll
    for (int p = 0; p < 2; ++p) {
      int row = ry + 32 * p;
      float4 vv = *(const float4*)&in[(size_t)(r0 + row) * C + c0 + cx * 4];
      tbuf[row][cx * 4 + 0] = vv.x;
      tbuf[row][cx * 4 + 1] = vv.y;
      tbuf[row][cx * 4 + 2] = vv.z;
      tbuf[row][cx * 4 + 3] = vv.w;
    }
    __syncthreads();
    // pack phase: proven round-0 code (unchanged)
    int tx = tid & 31, ty = tid >> 5;
#pragma unroll
    for (int i = 0; i < 4; ++i) {
      int cl = ty + 8 * i;
      unsigned lo = (unsigned short)f2bs(tbuf[2 * tx][cl]);
      unsigned hi = (unsigned short)f2bs(tbuf[2 * tx + 1][cl]);
      ((int*)op)[(((size_t)(c0 + cl) * R) + r0) / 2 + tx] = (int)(lo | (hi << 16));
    }
    return;
  }

  // ---- router part: 16 tokens, 16 lanes per token ----
  __shared__ float wr_t[E_NUM * D_DIM];  // [e][d], 16 KB
  __shared__ int h_cnt[E_NUM];
  __shared__ float psh[E_NUM];
  int rb = u;
  for (int i = tid; i < D_DIM * E_NUM; i += 256)
    wr_t[(i & 7) * D_DIM + (i >> 3)] = wr[i];  // wr is [d][e]
  if (tid < E_NUM) { h_cnt[tid] = 0; psh[tid] = 0.f; }
  __syncthreads();

  int r = tid >> 4, pp = tid & 15;
  int t = rb * 16 + r;
  const float* xr0 = x + (size_t)t * D_DIM;
  short* xw0 = xb + (size_t)t * D_DIM;
  float acc[8] = {0, 0, 0, 0, 0, 0, 0, 0};
#pragma unroll
  for (int j = 0; j < 8; ++j) {
    int d = j * 64 + pp * 4;  // 16 lanes cover 64 consecutive floats
    float4 xv = *(const float4*)(xr0 + d);
    short4 o;
    o.x = f2bs(xv.x); o.y = f2bs(xv.y); o.z = f2bs(xv.z); o.w = f2bs(xv.w);
    *(short4*)(xw0 + d) = o;
#pragma unroll
    for (int e = 0; e < 8; ++e) {
      float4 w = *(const float4*)&wr_t[e * D_DIM + d];
      acc[e] += xv.x * w.x + xv.y * w.y + xv.z * w.z + xv.w * w.w;
    }
  }
#pragma unroll
  for (int e = 0; e < 8; ++e) {
    acc[e] += __shfl_xor(acc[e], 1);
    acc[e] += __shfl_xor(acc[e], 2);
    acc[e] += __shfl_xor(acc[e], 4);
    acc[e] += __shfl_xor(acc[e], 8);
  }

  if (pp == 0) {
    float m = acc[0];
#pragma unroll
    for (int e = 1; e < 8; ++e) m = fmaxf(m, acc[e]);
    float p[8], s = 0.f;
#pragma unroll
    for (int e = 0; e < 8; ++e) { p[e] = expf(acc[e] - m); s += p[e]; }
    float inv = 1.f / s;
#pragma unroll
    for (int e = 0; e < 8; ++e) {
      p[e] *= inv;
      atomicAdd(&psh[e], p[e]);  // LDS scope
    }
    int i0 = 0;
#pragma unroll
    for (int e = 1; e < 8; ++e) if (p[e] > p[i0]) i0 = e;
    int i1 = (i0 == 0) ? 1 : 0;
#pragma unroll
    for (int e = 0; e < 8; ++e) if (e != i0 && p[e] > p[i1]) i1 = e;
    float ps = p[i0] + p[i1] + 1e-10f;
    float q0 = p[i0] / ps, q1 = p[i1] / ps;
    int l0 = atomicAdd(&h_cnt[i0], 1);  // LDS scope
    int l1 = atomicAdd(&h_cnt[i1], 1);
    tok_bkt[i0 * (RB_NUM * 16) + rb * 16 + l0] = t * 2 + 0;
    p_bkt[i0 * (RB_NUM * 16) + rb * 16 + l0] = q0;
    tok_bkt[i1 * (RB_NUM * 16) + rb * 16 + l1] = t * 2 + 1;
    p_bkt[i1 * (RB_NUM * 16) + rb * 16 + l1] = q1;
  }
  __syncthreads();
  if (tid < E_NUM) {
    cnt_blk[rb * 8 + tid] = h_cnt[tid];   // plain stores, fully owned
    psum_blk[rb * 8 + tid] = psh[tid];
  }
}

// ---------- route pack: 128 blocks = 8 experts x 16 rb-chunks ----------
__global__ void __launch_bounds__(256) route_pack_kernel(
    const int* __restrict__ cnt_blk, const int* __restrict__ tok_bkt,
    const float* __restrict__ p_bkt, int* __restrict__ dense_tok,
    float* __restrict__ dense_p, int* __restrict__ n_tot) {
  int e = blockIdx.x >> 4;
  int chunk = blockIdx.x & 15;
  int tid = threadIdx.x, lane = tid & 63, wid = tid >> 6;
  __shared__ int wsum[4];
  __shared__ int s_excl[16];
  __shared__ int s_cnt[16];
  int c = cnt_blk[tid * 8 + e];
  int inc = c;
#pragma unroll
  for (int ofs = 1; ofs < 64; ofs <<= 1) {
    int v = __shfl_up(inc, ofs);
    if (lane >= ofs) inc += v;
  }
  if (lane == 63) wsum[wid] = inc;
  __syncthreads();
  int pre = 0;
#pragma unroll
  for (int w = 0; w < 4; ++w) pre += (w < wid) ? wsum[w] : 0;
  int excl = inc + pre - c;
  if ((tid >> 4) == chunk) {
    s_excl[tid & 15] = excl;
    s_cnt[tid & 15] = c;
  }
  if (chunk == 0 && tid == 255) n_tot[e] = inc + pre;
  __syncthreads();
  int rbl = tid >> 4, i = tid & 15;
  int rb = chunk * 16 + rbl;
  if (i < s_cnt[rbl]) {
    int src = e * (RB_NUM * 16) + rb * 16 + i;
    int dst = e * N_TOK + s_excl[rbl] + i;
    dense_tok[dst] = tok_bkt[src];
    dense_p[dst] = p_bkt[src];
  }
}

// ---------- grouped gate/up GEMM (256 tok x 64 h tile, G+U fused) ----------
// A read DIRECT from global (xb L2-resident; de-swizzled addr = plain row
// chunk quad+ks*4) -- A no longer staged through LDS. B staged as before.
// LDS traffic per block-ktstep: 48KB write + 96KB read -> 16KB + 64KB.
__global__ void __launch_bounds__(256, 3) moe_gateup_kernel(
    const short* __restrict__ xb, const short* __restrict__ wg,
    const short* __restrict__ wu, const int* __restrict__ dense_tok,
    const float* __restrict__ dense_p, const int* __restrict__ n_tot,
    const float* __restrict__ psum_blk, short* __restrict__ act,
    float* __restrict__ out_loss) {
  int e = blockIdx.z;
  int tid = threadIdx.x;

  if (e == 8) {  // load-balance loss
    if (blockIdx.x || blockIdx.y) return;
    __shared__ float sums[8];
    if (tid < 8) sums[tid] = 0.f;
    __syncthreads();
#pragma unroll
    for (int ee = 0; ee < 8; ++ee)
      atomicAdd(&sums[ee], psum_blk[tid * 8 + ee]);
    __syncthreads();
    if (tid == 0) {
      float lb = 0.f;
#pragma unroll
      for (int ee = 0; ee < 8; ++ee) {
        float pe = sums[ee] / (float)N_TOK;
        lb += pe * logf(pe * 8.f + 1e-10f);
      }
      out_loss[0] = 8.f * lb;
    }
    return;
  }

  int n_e = n_tot[e];
  int rt = blockIdx.y;
  if (rt * 256 >= n_e) return;  // uniform early exit, one scalar load
  int h0 = blockIdx.x * 64;

  __shared__ __align__(16) short Bgs[64 * 64];   // 8 KB
  __shared__ __align__(16) short Bus[64 * 64];   // 8 KB
  __shared__ int s_row[256];
  __shared__ float s_pr[256];

  int lane = tid & 63, wid = tid >> 6;

  {
    int r = rt * 256 + tid;
    int srow = -1;
    float spr = 0.f;
    if (r < n_e) {
      srow = dense_tok[e * N_TOK + r];
      spr = dense_p[e * N_TOK + r];
    }
    s_row[tid] = srow;
    s_pr[tid] = spr;
  }
  __syncthreads();

  int cg = (lane & 7) ^ (lane >> 3);  // swizzled global chunk (B staging)
  int ml = lane & 15, quad = lane >> 4;
  int m0w = wid * 64;

  // per-lane direct-A row pointers: rows m0w + mf*16 + ml
  const short* aptr[4];
#pragma unroll
  for (int mf = 0; mf < 4; ++mf) {
    int row = s_row[m0w + mf * 16 + ml];
    int t = (row < 0) ? 0 : (row >> 1);
    aptr[mf] = xb + (size_t)t * D_DIM + quad * 8;
  }

  const short* baseB[4];
  short* ldsB;
  {
    const short* wB = ((wid & 2) ? wu : wg) + (size_t)e * H_DIM * D_DIM;
    int rb = (wid & 1) * 32;
    ldsB = ((wid & 2) ? Bus : Bgs) + rb * 64;
#pragma unroll
    for (int jj = 0; jj < 4; ++jj) {
      int h = h0 + rb + jj * 8 + (lane >> 3);
      baseB[jj] = wB + (size_t)h * D_DIM + cg * 8;
    }
  }

  f32x4 accG[4][4], accU[4][4];
#pragma unroll
  for (int mf = 0; mf < 4; ++mf)
#pragma unroll
    for (int nf = 0; nf < 4; ++nf) {
      accG[mf][nf] = (f32x4){0, 0, 0, 0};
      accU[mf][nf] = (f32x4){0, 0, 0, 0};
    }

  for (int kt = 0; kt < D_DIM / 64; ++kt) {
    int kb = kt * 64;
    // stage B (4 llds16/wave) and issue A global loads before the barrier
#pragma unroll
    for (int jj = 0; jj < 4; ++jj)
      llds16(baseB[jj] + kb, ldsB + jj * 512);
    short8 a[2][4];
#pragma unroll
    for (int ks = 0; ks < 2; ++ks)
#pragma unroll
      for (int mf = 0; mf < 4; ++mf)
        a[ks][mf] = *(const short8*)(aptr[mf] + kb + ks * 32);
    __syncthreads();
#pragma unroll
    for (int ks = 0; ks < 2; ++ks) {
      int cs = ((quad + ks * 4) ^ (ml & 7)) * 8;
      short8 bg[4], bu[4];
#pragma unroll
      for (int nf = 0; nf < 4; ++nf) {
        bg[nf] = *(const short8*)&Bgs[(nf * 16 + ml) * 64 + cs];
        bu[nf] = *(const short8*)&Bus[(nf * 16 + ml) * 64 + cs];
      }
#pragma unroll
      for (int mf = 0; mf < 4; ++mf)
#pragma unroll
        for (int nf = 0; nf < 4; ++nf) {
          accG[mf][nf] = __builtin_amdgcn_mfma_f32_16x16x32_bf16(a[ks][mf], bg[nf], accG[mf][nf], 0, 0, 0);
          accU[mf][nf] = __builtin_amdgcn_mfma_f32_16x16x32_bf16(a[ks][mf], bu[nf], accU[mf][nf], 0, 0, 0);
        }
    }
    __syncthreads();
  }

#pragma unroll
  for (int mf = 0; mf < 4; ++mf)
#pragma unroll
    for (int r = 0; r < 4; ++r) {
      int rl = m0w + mf * 16 + quad * 4 + r;
      int arow = s_row[rl];
      if (arow >= 0) {
        float pr = s_pr[rl];
#pragma unroll
        for (int nf = 0; nf < 4; ++nf) {
          float g = accG[mf][nf][r], u = accU[mf][nf][r];
          float val = pr * (g / (1.f + __expf(-g))) * u;
          act[(size_t)arow * H_DIM + h0 + nf * 16 + ml] = f2bs(val);
        }
      }
    }
}

// ---------- down GEMM: partial[ksb][t][d] = act-slice @ wd ----------
// 64tok x 256d tile (act read only 2x total), Ksplit=4 over blockIdx.z.
// 4 waves: each owns 64tok x 64d strip; both slots accumulate into one acc
// with the B fragment reused in-register. 48 KB LDS -> 3 blocks/CU.
__global__ void __launch_bounds__(256, 3) down_kernel(
    const short* __restrict__ act, const short* __restrict__ wd,
    float* __restrict__ partial) {
  __shared__ __align__(16) short As0[64 * 64];   // 8 KB (slot 0)
  __shared__ __align__(16) short As1[64 * 64];   // 8 KB (slot 1)
  __shared__ __align__(16) short Bs[256 * 64];   // 32 KB
  int d0 = blockIdx.x * 256;
  int t0 = blockIdx.y * 64;
  int ksb = blockIdx.z;  // h-chunks [ksb*8, ksb*8+8)
  int tid = threadIdx.x, lane = tid & 63, wid = tid >> 6;
  int cg = (lane & 7) ^ (lane >> 3);

  const short* baseA[4];
  const short* baseB[8];
  int slot = wid >> 1;
  int arow0 = (wid & 1) * 32;
#pragma unroll
  for (int jj = 0; jj < 4; ++jj) {
    int r = arow0 + jj * 8 + (lane >> 3);
    baseA[jj] = act + (size_t)(2 * (t0 + r) + slot) * H_DIM + cg * 8;
  }
#pragma unroll
  for (int jj = 0; jj < 8; ++jj) {
    int d = d0 + wid * 64 + jj * 8 + (lane >> 3);
    baseB[jj] = wd + (size_t)d * H_DIM + cg * 8;
  }
  short* ldsA = (slot ? As1 : As0) + arow0 * 64;

  int ml = lane & 15, quad = lane >> 4;
  int n0w = wid * 64;
  f32x4 acc[4][4];
#pragma unroll
  for (int mf = 0; mf < 4; ++mf)
#pragma unroll
    for (int nf = 0; nf < 4; ++nf) acc[mf][nf] = (f32x4){0, 0, 0, 0};

  for (int j = 0; j < 8; ++j) {
    int hb = (ksb * 8 + j) * 64;
#pragma unroll
    for (int jj = 0; jj < 4; ++jj)
      llds16(baseA[jj] + hb, ldsA + jj * 512);
#pragma unroll
    for (int jj = 0; jj < 8; ++jj)
      llds16(baseB[jj] + hb, Bs + wid * 4096 + jj * 512);
    __syncthreads();
#pragma unroll
    for (int ks = 0; ks < 2; ++ks) {
      int cs = ((quad + ks * 4) ^ (ml & 7)) * 8;
      short8 a0[4], a1[4], b[4];
#pragma unroll
      for (int mf = 0; mf < 4; ++mf) {
        a0[mf] = *(const short8*)&As0[(mf * 16 + ml) * 64 + cs];
        a1[mf] = *(const short8*)&As1[(mf * 16 + ml) * 64 + cs];
      }
#pragma unroll
      for (int nf = 0; nf < 4; ++nf)
        b[nf] = *(const short8*)&Bs[(n0w + nf * 16 + ml) * 64 + cs];
#pragma unroll
      for (int mf = 0; mf < 4; ++mf)
#pragma unroll
        for (int nf = 0; nf < 4; ++nf) {
          acc[mf][nf] = __builtin_amdgcn_mfma_f32_16x16x32_bf16(a0[mf], b[nf], acc[mf][nf], 0, 0, 0);
          acc[mf][nf] = __builtin_amdgcn_mfma_f32_16x16x32_bf16(a1[mf], b[nf], acc[mf][nf], 0, 0, 0);
        }
    }
    __syncthreads();
  }

  float* pout = partial + (size_t)ksb * N_TOK * D_DIM;
#pragma unroll
  for (int mf = 0; mf < 4; ++mf)
#pragma unroll
    for (int r = 0; r < 4; ++r) {
      int t = t0 + mf * 16 + quad * 4 + r;
#pragma unroll
      for (int nf = 0; nf < 4; ++nf)
        pout[(size_t)t * D_DIM + d0 + n0w + nf * 16 + ml] = acc[mf][nf][r];
    }
}

// ---------- split-K reduce: out = sum of 4 partials ----------
__global__ void __launch_bounds__(256) reduce_kernel(
    const float* __restrict__ partial, float* __restrict__ out) {
  int i = blockIdx.x * 256 + threadIdx.x;  // float4 index
  const int Q = N_TOK * D_DIM / 4;
  const float4* p = (const float4*)partial;
  float4 a = p[i], b = p[i + Q], c = p[i + 2 * Q], d = p[i + 3 * Q];
  float4 r = {a.x + b.x + c.x + d.x, a.y + b.y + c.y + d.y,
              a.z + b.z + c.z + d.z, a.w + b.w + c.w + d.w};
  ((float4*)out)[i] = r;
}

extern "C" void kernel_launch(void* const* d_in, const int* in_sizes, int n_in,
                              void* d_out, int out_size, void* d_ws, size_t ws_size,
                              hipStream_t stream) {
  const float* x = (const float*)d_in[0];
  const float* wr = (const float*)d_in[1];
  const float* wg = (const float*)d_in[2];
  const float* wu = (const float*)d_in[3];
  const float* wd = (const float*)d_in[4];
  float* out = (float*)d_out;

  char* ws = (char*)d_ws;
  size_t off = 0;
  auto alloc = [&](size_t bytes) {
    char* p = ws + off;
    off += (bytes + 255) & ~(size_t)255;
    return p;
  };
  short* xb = (short*)alloc((size_t)N_TOK * D_DIM * 2);
  short* wgb = (short*)alloc((size_t)E_NUM * H_DIM * D_DIM * 2);  // [e*H+h][d]
  short* wub = (short*)alloc((size_t)E_NUM * H_DIM * D_DIM * 2);
  short* wdb = (short*)alloc((size_t)D_DIM * H_DIM * 2);          // [d][h]
  short* act = (short*)alloc((size_t)N_TOK * 2 * H_DIM * 2);      // [2t+slot][H]
  float* partial = (float*)alloc((size_t)4 * N_TOK * D_DIM * 4);  // split-K partials
  int* cnt_blk = (int*)alloc((size_t)RB_NUM * E_NUM * 4);
  int* tok_bkt = (int*)alloc((size_t)E_NUM * RB_NUM * 16 * 4);
  float* p_bkt = (float*)alloc((size_t)E_NUM * RB_NUM * 16 * 4);
  float* psum_blk = (float*)alloc((size_t)RB_NUM * E_NUM * 4);
  int* dense_tok = (int*)alloc((size_t)E_NUM * N_TOK * 4);
  float* dense_p = (float*)alloc((size_t)E_NUM * N_TOK * 4);
  int* n_tot = (int*)alloc((size_t)E_NUM * 4);

  prep_router_kernel<<<RB_NUM + TP_NUM, 256, 0, stream>>>(
      wg, wu, wd, x, wr, wgb, wub, wdb, xb, cnt_blk, tok_bkt, p_bkt, psum_blk);
  route_pack_kernel<<<E_NUM * 16, 256, 0, stream>>>(
      cnt_blk, tok_bkt, p_bkt, dense_tok, dense_p, n_tot);
  moe_gateup_kernel<<<dim3(H_DIM / 64, N_TOK / 256, E_NUM + 1), 256, 0, stream>>>(
      xb, wgb, wub, dense_tok, dense_p, n_tot, psum_blk, act,
      out + (size_t)N_TOK * D_DIM);
  down_kernel<<<dim3(D_DIM / 256, N_TOK / 64, 4), 256, 0, stream>>>(
      act, wdb, partial);
  reduce_kernel<<<N_TOK * D_DIM / 4 / 256, 256, 0, stream>>>(partial, out);
}

// Round 9
// 382.519 us; speedup vs baseline: 1.0572x; 1.0572x over previous
//
#include <hip/hip_runtime.h>
#include <hip/hip_bf16.h>

#define N_TOK 4096
#define D_DIM 512
#define E_NUM 8
#define H_DIM 2048
#define RB_NUM 256   // router blocks (16 tokens each)
#define TP_NUM 8704  // transpose tiles (64x32): 4096 wg + 4096 wu + 512 wd

typedef __attribute__((ext_vector_type(8))) short short8;
typedef __attribute__((ext_vector_type(4))) float f32x4;

__device__ inline short f2bs(float f) {
  __hip_bfloat16 h = __float2bfloat16(f);
  return *reinterpret_cast<short*>(&h);
}

// async global->LDS, 16 B per lane; lds dest is wave-uniform base + lane*16
__device__ inline void llds16(const short* g, short* l) {
  __builtin_amdgcn_global_load_lds(
      (const __attribute__((address_space(1))) void*)g,
      (__attribute__((address_space(3))) void*)l, 16, 0, 0);
}

// ---------- fused prep+router ----------
// blocks [0,256): router (16 tokens each, 16 lanes/token)
// blocks [256, 256+8704): 64r x 32c transpose tiles (wg/wu/wd)
// load phase: float4 (16 B/lane, 2 rounds); pack phase: round-0 proven scalar
__global__ void __launch_bounds__(256) prep_router_kernel(
    const float* __restrict__ wg, const float* __restrict__ wu,
    const float* __restrict__ wd, const float* __restrict__ x,
    const float* __restrict__ wr, short* __restrict__ wgb,
    short* __restrict__ wub, short* __restrict__ wdb, short* __restrict__ xb,
    int* __restrict__ cnt_blk, int* __restrict__ tok_bkt,
    float* __restrict__ p_bkt, float* __restrict__ psum_blk) {
  int u = blockIdx.x;
  int tid = threadIdx.x;

  if (u >= RB_NUM) {
    // ---- 64r x 32c transpose-convert, int-packed bf16 writes ----
    __shared__ float tbuf[64][33];
    int v = u - RB_NUM;
    const float* in;
    short* op;
    int R, C, c0, r0;
    if (v < 8192) {
      in = (v < 4096) ? wg : wu;
      op = (v < 4096) ? wgb : wub;
      int w = v & 4095;
      R = D_DIM; C = E_NUM * H_DIM;
      c0 = (w & 511) * 32; r0 = (w >> 9) * 64;
    } else {
      in = wd; op = wdb;
      int w = v - 8192;
      R = H_DIM; C = D_DIM;
      c0 = (w & 15) * 32; r0 = (w >> 4) * 64;
    }
    // load phase: float4 per lane; covers rows 0..63, cols 0..31
    int cx = tid & 7, ry = tid >> 3;  // cx: float4-col 0..7, ry: row 0..31
#pragma unroll
    for (int p = 0; p < 2; ++p) {
      int row = ry + 32 * p;
      float4 vv = *(const float4*)&in[(size_t)(r0 + row) * C + c0 + cx * 4];
      tbuf[row][cx * 4 + 0] = vv.x;
      tbuf[row][cx * 4 + 1] = vv.y;
      tbuf[row][cx * 4 + 2] = vv.z;
      tbuf[row][cx * 4 + 3] = vv.w;
    }
    __syncthreads();
    // pack phase: proven round-0 code (unchanged)
    int tx = tid & 31, ty = tid >> 5;
#pragma unroll
    for (int i = 0; i < 4; ++i) {
      int cl = ty + 8 * i;
      unsigned lo = (unsigned short)f2bs(tbuf[2 * tx][cl]);
      unsigned hi = (unsigned short)f2bs(tbuf[2 * tx + 1][cl]);
      ((int*)op)[(((size_t)(c0 + cl) * R) + r0) / 2 + tx] = (int)(lo | (hi << 16));
    }
    return;
  }

  // ---- router part: 16 tokens, 16 lanes per token ----
  __shared__ float wr_t[E_NUM * D_DIM];  // [e][d], 16 KB
  __shared__ int h_cnt[E_NUM];
  __shared__ float psh[E_NUM];
  int rb = u;
  for (int i = tid; i < D_DIM * E_NUM; i += 256)
    wr_t[(i & 7) * D_DIM + (i >> 3)] = wr[i];  // wr is [d][e]
  if (tid < E_NUM) { h_cnt[tid] = 0; psh[tid] = 0.f; }
  __syncthreads();

  int r = tid >> 4, pp = tid & 15;
  int t = rb * 16 + r;
  const float* xr0 = x + (size_t)t * D_DIM;
  short* xw0 = xb + (size_t)t * D_DIM;
  float acc[8] = {0, 0, 0, 0, 0, 0, 0, 0};
#pragma unroll
  for (int j = 0; j < 8; ++j) {
    int d = j * 64 + pp * 4;  // 16 lanes cover 64 consecutive floats
    float4 xv = *(const float4*)(xr0 + d);
    short4 o;
    o.x = f2bs(xv.x); o.y = f2bs(xv.y); o.z = f2bs(xv.z); o.w = f2bs(xv.w);
    *(short4*)(xw0 + d) = o;
#pragma unroll
    for (int e = 0; e < 8; ++e) {
      float4 w = *(const float4*)&wr_t[e * D_DIM + d];
      acc[e] += xv.x * w.x + xv.y * w.y + xv.z * w.z + xv.w * w.w;
    }
  }
#pragma unroll
  for (int e = 0; e < 8; ++e) {
    acc[e] += __shfl_xor(acc[e], 1);
    acc[e] += __shfl_xor(acc[e], 2);
    acc[e] += __shfl_xor(acc[e], 4);
    acc[e] += __shfl_xor(acc[e], 8);
  }

  if (pp == 0) {
    float m = acc[0];
#pragma unroll
    for (int e = 1; e < 8; ++e) m = fmaxf(m, acc[e]);
    float p[8], s = 0.f;
#pragma unroll
    for (int e = 0; e < 8; ++e) { p[e] = expf(acc[e] - m); s += p[e]; }
    float inv = 1.f / s;
#pragma unroll
    for (int e = 0; e < 8; ++e) {
      p[e] *= inv;
      atomicAdd(&psh[e], p[e]);  // LDS scope
    }
    int i0 = 0;
#pragma unroll
    for (int e = 1; e < 8; ++e) if (p[e] > p[i0]) i0 = e;
    int i1 = (i0 == 0) ? 1 : 0;
#pragma unroll
    for (int e = 0; e < 8; ++e) if (e != i0 && p[e] > p[i1]) i1 = e;
    float ps = p[i0] + p[i1] + 1e-10f;
    float q0 = p[i0] / ps, q1 = p[i1] / ps;
    int l0 = atomicAdd(&h_cnt[i0], 1);  // LDS scope
    int l1 = atomicAdd(&h_cnt[i1], 1);
    tok_bkt[i0 * (RB_NUM * 16) + rb * 16 + l0] = t * 2 + 0;
    p_bkt[i0 * (RB_NUM * 16) + rb * 16 + l0] = q0;
    tok_bkt[i1 * (RB_NUM * 16) + rb * 16 + l1] = t * 2 + 1;
    p_bkt[i1 * (RB_NUM * 16) + rb * 16 + l1] = q1;
  }
  __syncthreads();
  if (tid < E_NUM) {
    cnt_blk[rb * 8 + tid] = h_cnt[tid];   // plain stores, fully owned
    psum_blk[rb * 8 + tid] = psh[tid];
  }
}

// ---------- route pack: 128 blocks = 8 experts x 16 rb-chunks ----------
__global__ void __launch_bounds__(256) route_pack_kernel(
    const int* __restrict__ cnt_blk, const int* __restrict__ tok_bkt,
    const float* __restrict__ p_bkt, int* __restrict__ dense_tok,
    float* __restrict__ dense_p, int* __restrict__ n_tot) {
  int e = blockIdx.x >> 4;
  int chunk = blockIdx.x & 15;
  int tid = threadIdx.x, lane = tid & 63, wid = tid >> 6;
  __shared__ int wsum[4];
  __shared__ int s_excl[16];
  __shared__ int s_cnt[16];
  int c = cnt_blk[tid * 8 + e];
  int inc = c;
#pragma unroll
  for (int ofs = 1; ofs < 64; ofs <<= 1) {
    int v = __shfl_up(inc, ofs);
    if (lane >= ofs) inc += v;
  }
  if (lane == 63) wsum[wid] = inc;
  __syncthreads();
  int pre = 0;
#pragma unroll
  for (int w = 0; w < 4; ++w) pre += (w < wid) ? wsum[w] : 0;
  int excl = inc + pre - c;
  if ((tid >> 4) == chunk) {
    s_excl[tid & 15] = excl;
    s_cnt[tid & 15] = c;
  }
  if (chunk == 0 && tid == 255) n_tot[e] = inc + pre;
  __syncthreads();
  int rbl = tid >> 4, i = tid & 15;
  int rb = chunk * 16 + rbl;
  if (i < s_cnt[rbl]) {
    int src = e * (RB_NUM * 16) + rb * 16 + i;
    int dst = e * N_TOK + s_excl[rbl] + i;
    dense_tok[dst] = tok_bkt[src];
    dense_p[dst] = p_bkt[src];
  }
}

// ---------- grouped gate/up GEMM (256 tok x 64 h tile, G+U fused) ----------
// A staged via llds16 (coalesced 128 B/token, proven path). B read DIRECT from
// global: rows h0+nf*16+ml are consecutive; all 4 waves share the same 16 KB
// window per kt -> L1-served. With B out of LDS everything is wave-private,
// so NO kt-loop barriers: wave-scoped vmcnt(0) after its own llds16 suffices.
__global__ void __launch_bounds__(256, 3) moe_gateup_kernel(
    const short* __restrict__ xb, const short* __restrict__ wg,
    const short* __restrict__ wu, const int* __restrict__ dense_tok,
    const float* __restrict__ dense_p, const int* __restrict__ n_tot,
    const float* __restrict__ psum_blk, short* __restrict__ act,
    float* __restrict__ out_loss) {
  int e = blockIdx.z;
  int tid = threadIdx.x;

  if (e == 8) {  // load-balance loss
    if (blockIdx.x || blockIdx.y) return;
    __shared__ float sums[8];
    if (tid < 8) sums[tid] = 0.f;
    __syncthreads();
#pragma unroll
    for (int ee = 0; ee < 8; ++ee)
      atomicAdd(&sums[ee], psum_blk[tid * 8 + ee]);
    __syncthreads();
    if (tid == 0) {
      float lb = 0.f;
#pragma unroll
      for (int ee = 0; ee < 8; ++ee) {
        float pe = sums[ee] / (float)N_TOK;
        lb += pe * logf(pe * 8.f + 1e-10f);
      }
      out_loss[0] = 8.f * lb;
    }
    return;
  }

  int n_e = n_tot[e];
  int rt = blockIdx.y;
  if (rt * 256 >= n_e) return;  // uniform early exit, one scalar load
  int h0 = blockIdx.x * 64;

  __shared__ __align__(16) short As[256 * 64];   // 32 KB (wave-private slices)
  __shared__ int s_row[256];
  __shared__ float s_pr[256];

  int lane = tid & 63, wid = tid >> 6;

  {
    int r = rt * 256 + tid;
    int srow = -1;
    float spr = 0.f;
    if (r < n_e) {
      srow = dense_tok[e * N_TOK + r];
      spr = dense_p[e * N_TOK + r];
    }
    s_row[tid] = srow;
    s_pr[tid] = spr;
  }
  __syncthreads();

  int cg = (lane & 7) ^ (lane >> 3);  // swizzled global chunk (A staging)
  const short* baseA[8];
#pragma unroll
  for (int jj = 0; jj < 8; ++jj) {
    int r = wid * 64 + jj * 8 + (lane >> 3);
    int row = s_row[r];
    int t = (row < 0) ? 0 : (row >> 1);
    baseA[jj] = xb + (size_t)t * D_DIM + cg * 8;
  }

  int ml = lane & 15, quad = lane >> 4;
  int m0w = wid * 64;

  // direct-B per-lane row pointers (consecutive h rows; de-swizzled chunk
  // for row nf*16+ml at read-chunk (quad+ks*4)^(ml&7) is plain quad+ks*4)
  const short* pBg = wg + (size_t)e * H_DIM * D_DIM + (size_t)(h0 + ml) * D_DIM + quad * 8;
  const short* pBu = wu + (size_t)e * H_DIM * D_DIM + (size_t)(h0 + ml) * D_DIM + quad * 8;

  f32x4 accG[4][4], accU[4][4];
#pragma unroll
  for (int mf = 0; mf < 4; ++mf)
#pragma unroll
    for (int nf = 0; nf < 4; ++nf) {
      accG[mf][nf] = (f32x4){0, 0, 0, 0};
      accU[mf][nf] = (f32x4){0, 0, 0, 0};
    }

  for (int kt = 0; kt < D_DIM / 64; ++kt) {
    int kb = kt * 64;
#pragma unroll
    for (int jj = 0; jj < 8; ++jj)
      llds16(baseA[jj] + kb, As + wid * 4096 + jj * 512);
    // wave-scoped: wait own global->LDS writes (no cross-wave LDS sharing)
    asm volatile("s_waitcnt vmcnt(0)" ::: "memory");
#pragma unroll
    for (int ks = 0; ks < 2; ++ks) {
      int cs = ((quad + ks * 4) ^ (ml & 7)) * 8;
      short8 a[4], bg[4], bu[4];
#pragma unroll
      for (int mf = 0; mf < 4; ++mf)
        a[mf] = *(const short8*)&As[(m0w + mf * 16 + ml) * 64 + cs];
#pragma unroll
      for (int nf = 0; nf < 4; ++nf) {
        bg[nf] = *(const short8*)(pBg + (size_t)nf * 16 * D_DIM + kb + ks * 32);
        bu[nf] = *(const short8*)(pBu + (size_t)nf * 16 * D_DIM + kb + ks * 32);
      }
#pragma unroll
      for (int mf = 0; mf < 4; ++mf)
#pragma unroll
        for (int nf = 0; nf < 4; ++nf) {
          accG[mf][nf] = __builtin_amdgcn_mfma_f32_16x16x32_bf16(a[mf], bg[nf], accG[mf][nf], 0, 0, 0);
          accU[mf][nf] = __builtin_amdgcn_mfma_f32_16x16x32_bf16(a[mf], bu[nf], accU[mf][nf], 0, 0, 0);
        }
    }
  }

#pragma unroll
  for (int mf = 0; mf < 4; ++mf)
#pragma unroll
    for (int r = 0; r < 4; ++r) {
      int rl = m0w + mf * 16 + quad * 4 + r;
      int arow = s_row[rl];
      if (arow >= 0) {
        float pr = s_pr[rl];
#pragma unroll
        for (int nf = 0; nf < 4; ++nf) {
          float g = accG[mf][nf][r], u = accU[mf][nf][r];
          float val = pr * (g / (1.f + __expf(-g))) * u;
          act[(size_t)arow * H_DIM + h0 + nf * 16 + ml] = f2bs(val);
        }
      }
    }
}

// ---------- down GEMM: partial[ksb][t][d] = act-slice @ wd ----------
// 64tok x 256d tile (act read only 2x total), Ksplit=4 over blockIdx.z.
// 4 waves: each owns 64tok x 64d strip; both slots accumulate into one acc
// with the B fragment reused in-register. 48 KB LDS -> 3 blocks/CU.
__global__ void __launch_bounds__(256, 3) down_kernel(
    const short* __restrict__ act, const short* __restrict__ wd,
    float* __restrict__ partial) {
  __shared__ __align__(16) short As0[64 * 64];   // 8 KB (slot 0)
  __shared__ __align__(16) short As1[64 * 64];   // 8 KB (slot 1)
  __shared__ __align__(16) short Bs[256 * 64];   // 32 KB
  int d0 = blockIdx.x * 256;
  int t0 = blockIdx.y * 64;
  int ksb = blockIdx.z;  // h-chunks [ksb*8, ksb*8+8)
  int tid = threadIdx.x, lane = tid & 63, wid = tid >> 6;
  int cg = (lane & 7) ^ (lane >> 3);

  const short* baseA[4];
  const short* baseB[8];
  int slot = wid >> 1;
  int arow0 = (wid & 1) * 32;
#pragma unroll
  for (int jj = 0; jj < 4; ++jj) {
    int r = arow0 + jj * 8 + (lane >> 3);
    baseA[jj] = act + (size_t)(2 * (t0 + r) + slot) * H_DIM + cg * 8;
  }
#pragma unroll
  for (int jj = 0; jj < 8; ++jj) {
    int d = d0 + wid * 64 + jj * 8 + (lane >> 3);
    baseB[jj] = wd + (size_t)d * H_DIM + cg * 8;
  }
  short* ldsA = (slot ? As1 : As0) + arow0 * 64;

  int ml = lane & 15, quad = lane >> 4;
  int n0w = wid * 64;
  f32x4 acc[4][4];
#pragma unroll
  for (int mf = 0; mf < 4; ++mf)
#pragma unroll
    for (int nf = 0; nf < 4; ++nf) acc[mf][nf] = (f32x4){0, 0, 0, 0};

  for (int j = 0; j < 8; ++j) {
    int hb = (ksb * 8 + j) * 64;
#pragma unroll
    for (int jj = 0; jj < 4; ++jj)
      llds16(baseA[jj] + hb, ldsA + jj * 512);
#pragma unroll
    for (int jj = 0; jj < 8; ++jj)
      llds16(baseB[jj] + hb, Bs + wid * 4096 + jj * 512);
    __syncthreads();
#pragma unroll
    for (int ks = 0; ks < 2; ++ks) {
      int cs = ((quad + ks * 4) ^ (ml & 7)) * 8;
      short8 a0[4], a1[4], b[4];
#pragma unroll
      for (int mf = 0; mf < 4; ++mf) {
        a0[mf] = *(const short8*)&As0[(mf * 16 + ml) * 64 + cs];
        a1[mf] = *(const short8*)&As1[(mf * 16 + ml) * 64 + cs];
      }
#pragma unroll
      for (int nf = 0; nf < 4; ++nf)
        b[nf] = *(const short8*)&Bs[(n0w + nf * 16 + ml) * 64 + cs];
#pragma unroll
      for (int mf = 0; mf < 4; ++mf)
#pragma unroll
        for (int nf = 0; nf < 4; ++nf) {
          acc[mf][nf] = __builtin_amdgcn_mfma_f32_16x16x32_bf16(a0[mf], b[nf], acc[mf][nf], 0, 0, 0);
          acc[mf][nf] = __builtin_amdgcn_mfma_f32_16x16x32_bf16(a1[mf], b[nf], acc[mf][nf], 0, 0, 0);
        }
    }
    __syncthreads();
  }

  float* pout = partial + (size_t)ksb * N_TOK * D_DIM;
#pragma unroll
  for (int mf = 0; mf < 4; ++mf)
#pragma unroll
    for (int r = 0; r < 4; ++r) {
      int t = t0 + mf * 16 + quad * 4 + r;
#pragma unroll
      for (int nf = 0; nf < 4; ++nf)
        pout[(size_t)t * D_DIM + d0 + n0w + nf * 16 + ml] = acc[mf][nf][r];
    }
}

// ---------- split-K reduce: out = sum of 4 partials ----------
__global__ void __launch_bounds__(256) reduce_kernel(
    const float* __restrict__ partial, float* __restrict__ out) {
  int i = blockIdx.x * 256 + threadIdx.x;  // float4 index
  const int Q = N_TOK * D_DIM / 4;
  const float4* p = (const float4*)partial;
  float4 a = p[i], b = p[i + Q], c = p[i + 2 * Q], d = p[i + 3 * Q];
  float4 r = {a.x + b.x + c.x + d.x, a.y + b.y + c.y + d.y,
              a.z + b.z + c.z + d.z, a.w + b.w + c.w + d.w};
  ((float4*)out)[i] = r;
}

extern "C" void kernel_launch(void* const* d_in, const int* in_sizes, int n_in,
                              void* d_out, int out_size, void* d_ws, size_t ws_size,
                              hipStream_t stream) {
  const float* x = (const float*)d_in[0];
  const float* wr = (const float*)d_in[1];
  const float* wg = (const float*)d_in[2];
  const float* wu = (const float*)d_in[3];
  const float* wd = (const float*)d_in[4];
  float* out = (float*)d_out;

  char* ws = (char*)d_ws;
  size_t off = 0;
  auto alloc = [&](size_t bytes) {
    char* p = ws + off;
    off += (bytes + 255) & ~(size_t)255;
    return p;
  };
  short* xb = (short*)alloc((size_t)N_TOK * D_DIM * 2);
  short* wgb = (short*)alloc((size_t)E_NUM * H_DIM * D_DIM * 2);  // [e*H+h][d]
  short* wub = (short*)alloc((size_t)E_NUM * H_DIM * D_DIM * 2);
  short* wdb = (short*)alloc((size_t)D_DIM * H_DIM * 2);          // [d][h]
  short* act = (short*)alloc((size_t)N_TOK * 2 * H_DIM * 2);      // [2t+slot][H]
  float* partial = (float*)alloc((size_t)4 * N_TOK * D_DIM * 4);  // split-K partials
  int* cnt_blk = (int*)alloc((size_t)RB_NUM * E_NUM * 4);
  int* tok_bkt = (int*)alloc((size_t)E_NUM * RB_NUM * 16 * 4);
  float* p_bkt = (float*)alloc((size_t)E_NUM * RB_NUM * 16 * 4);
  float* psum_blk = (float*)alloc((size_t)RB_NUM * E_NUM * 4);
  int* dense_tok = (int*)alloc((size_t)E_NUM * N_TOK * 4);
  float* dense_p = (float*)alloc((size_t)E_NUM * N_TOK * 4);
  int* n_tot = (int*)alloc((size_t)E_NUM * 4);

  prep_router_kernel<<<RB_NUM + TP_NUM, 256, 0, stream>>>(
      wg, wu, wd, x, wr, wgb, wub, wdb, xb, cnt_blk, tok_bkt, p_bkt, psum_blk);
  route_pack_kernel<<<E_NUM * 16, 256, 0, stream>>>(
      cnt_blk, tok_bkt, p_bkt, dense_tok, dense_p, n_tot);
  moe_gateup_kernel<<<dim3(H_DIM / 64, N_TOK / 256, E_NUM + 1), 256, 0, stream>>>(
      xb, wgb, wub, dense_tok, dense_p, n_tot, psum_blk, act,
      out + (size_t)N_TOK * D_DIM);
  down_kernel<<<dim3(D_DIM / 256, N_TOK / 64, 4), 256, 0, stream>>>(
      act, wdb, partial);
  reduce_kernel<<<N_TOK * D_DIM / 4 / 256, 256, 0, stream>>>(partial, out);
}

// Round 10
// 207.541 us; speedup vs baseline: 1.9486x; 1.8431x over previous
//
#include <hip/hip_runtime.h>
#include <hip/hip_bf16.h>

#define N_TOK 4096
#define D_DIM 512
#define E_NUM 8
#define H_DIM 2048
#define RB_NUM 256   // router blocks (16 tokens each)
#define TP_NUM 8704  // transpose tiles (64x32): 4096 wg + 4096 wu + 512 wd

typedef __attribute__((ext_vector_type(8))) short short8;
typedef __attribute__((ext_vector_type(4))) float f32x4;

__device__ inline short f2bs(float f) {
  __hip_bfloat16 h = __float2bfloat16(f);
  return *reinterpret_cast<short*>(&h);
}

// async global->LDS, 16 B per lane; lds dest is wave-uniform base + lane*16
__device__ inline void llds16(const short* g, short* l) {
  __builtin_amdgcn_global_load_lds(
      (const __attribute__((address_space(1))) void*)g,
      (__attribute__((address_space(3))) void*)l, 16, 0, 0);
}

// ---------- fused prep+router ----------
// blocks [0,256): router (16 tokens each, 16 lanes/token)
// blocks [256, 256+8704): 64r x 32c transpose tiles (wg/wu/wd)
// load phase: float4 (16 B/lane, 2 rounds); pack phase: round-0 proven scalar
__global__ void __launch_bounds__(256) prep_router_kernel(
    const float* __restrict__ wg, const float* __restrict__ wu,
    const float* __restrict__ wd, const float* __restrict__ x,
    const float* __restrict__ wr, short* __restrict__ wgb,
    short* __restrict__ wub, short* __restrict__ wdb, short* __restrict__ xb,
    int* __restrict__ cnt_blk, int* __restrict__ tok_bkt,
    float* __restrict__ p_bkt, float* __restrict__ psum_blk) {
  int u = blockIdx.x;
  int tid = threadIdx.x;

  if (u >= RB_NUM) {
    // ---- 64r x 32c transpose-convert, int-packed bf16 writes ----
    __shared__ float tbuf[64][33];
    int v = u - RB_NUM;
    const float* in;
    short* op;
    int R, C, c0, r0;
    if (v < 8192) {
      in = (v < 4096) ? wg : wu;
      op = (v < 4096) ? wgb : wub;
      int w = v & 4095;
      R = D_DIM; C = E_NUM * H_DIM;
      c0 = (w & 511) * 32; r0 = (w >> 9) * 64;
    } else {
      in = wd; op = wdb;
      int w = v - 8192;
      R = H_DIM; C = D_DIM;
      c0 = (w & 15) * 32; r0 = (w >> 4) * 64;
    }
    // load phase: float4 per lane; covers rows 0..63, cols 0..31
    int cx = tid & 7, ry = tid >> 3;  // cx: float4-col 0..7, ry: row 0..31
#pragma unroll
    for (int p = 0; p < 2; ++p) {
      int row = ry + 32 * p;
      float4 vv = *(const float4*)&in[(size_t)(r0 + row) * C + c0 + cx * 4];
      tbuf[row][cx * 4 + 0] = vv.x;
      tbuf[row][cx * 4 + 1] = vv.y;
      tbuf[row][cx * 4 + 2] = vv.z;
      tbuf[row][cx * 4 + 3] = vv.w;
    }
    __syncthreads();
    // pack phase: proven round-0 code (unchanged)
    int tx = tid & 31, ty = tid >> 5;
#pragma unroll
    for (int i = 0; i < 4; ++i) {
      int cl = ty + 8 * i;
      unsigned lo = (unsigned short)f2bs(tbuf[2 * tx][cl]);
      unsigned hi = (unsigned short)f2bs(tbuf[2 * tx + 1][cl]);
      ((int*)op)[(((size_t)(c0 + cl) * R) + r0) / 2 + tx] = (int)(lo | (hi << 16));
    }
    return;
  }

  // ---- router part: 16 tokens, 16 lanes per token ----
  __shared__ float wr_t[E_NUM * D_DIM];  // [e][d], 16 KB
  __shared__ int h_cnt[E_NUM];
  __shared__ float psh[E_NUM];
  int rb = u;
  for (int i = tid; i < D_DIM * E_NUM; i += 256)
    wr_t[(i & 7) * D_DIM + (i >> 3)] = wr[i];  // wr is [d][e]
  if (tid < E_NUM) { h_cnt[tid] = 0; psh[tid] = 0.f; }
  __syncthreads();

  int r = tid >> 4, pp = tid & 15;
  int t = rb * 16 + r;
  const float* xr0 = x + (size_t)t * D_DIM;
  short* xw0 = xb + (size_t)t * D_DIM;
  float acc[8] = {0, 0, 0, 0, 0, 0, 0, 0};
#pragma unroll
  for (int j = 0; j < 8; ++j) {
    int d = j * 64 + pp * 4;  // 16 lanes cover 64 consecutive floats
    float4 xv = *(const float4*)(xr0 + d);
    short4 o;
    o.x = f2bs(xv.x); o.y = f2bs(xv.y); o.z = f2bs(xv.z); o.w = f2bs(xv.w);
    *(short4*)(xw0 + d) = o;
#pragma unroll
    for (int e = 0; e < 8; ++e) {
      float4 w = *(const float4*)&wr_t[e * D_DIM + d];
      acc[e] += xv.x * w.x + xv.y * w.y + xv.z * w.z + xv.w * w.w;
    }
  }
#pragma unroll
  for (int e = 0; e < 8; ++e) {
    acc[e] += __shfl_xor(acc[e], 1);
    acc[e] += __shfl_xor(acc[e], 2);
    acc[e] += __shfl_xor(acc[e], 4);
    acc[e] += __shfl_xor(acc[e], 8);
  }

  if (pp == 0) {
    float m = acc[0];
#pragma unroll
    for (int e = 1; e < 8; ++e) m = fmaxf(m, acc[e]);
    float p[8], s = 0.f;
#pragma unroll
    for (int e = 0; e < 8; ++e) { p[e] = expf(acc[e] - m); s += p[e]; }
    float inv = 1.f / s;
#pragma unroll
    for (int e = 0; e < 8; ++e) {
      p[e] *= inv;
      atomicAdd(&psh[e], p[e]);  // LDS scope
    }
    int i0 = 0;
#pragma unroll
    for (int e = 1; e < 8; ++e) if (p[e] > p[i0]) i0 = e;
    int i1 = (i0 == 0) ? 1 : 0;
#pragma unroll
    for (int e = 0; e < 8; ++e) if (e != i0 && p[e] > p[i1]) i1 = e;
    float ps = p[i0] + p[i1] + 1e-10f;
    float q0 = p[i0] / ps, q1 = p[i1] / ps;
    int l0 = atomicAdd(&h_cnt[i0], 1);  // LDS scope
    int l1 = atomicAdd(&h_cnt[i1], 1);
    tok_bkt[i0 * (RB_NUM * 16) + rb * 16 + l0] = t * 2 + 0;
    p_bkt[i0 * (RB_NUM * 16) + rb * 16 + l0] = q0;
    tok_bkt[i1 * (RB_NUM * 16) + rb * 16 + l1] = t * 2 + 1;
    p_bkt[i1 * (RB_NUM * 16) + rb * 16 + l1] = q1;
  }
  __syncthreads();
  if (tid < E_NUM) {
    cnt_blk[rb * 8 + tid] = h_cnt[tid];   // plain stores, fully owned
    psum_blk[rb * 8 + tid] = psh[tid];
  }
}

// ---------- route pack: 128 blocks = 8 experts x 16 rb-chunks ----------
__global__ void __launch_bounds__(256) route_pack_kernel(
    const int* __restrict__ cnt_blk, const int* __restrict__ tok_bkt,
    const float* __restrict__ p_bkt, int* __restrict__ dense_tok,
    float* __restrict__ dense_p, int* __restrict__ n_tot) {
  int e = blockIdx.x >> 4;
  int chunk = blockIdx.x & 15;
  int tid = threadIdx.x, lane = tid & 63, wid = tid >> 6;
  __shared__ int wsum[4];
  __shared__ int s_excl[16];
  __shared__ int s_cnt[16];
  int c = cnt_blk[tid * 8 + e];
  int inc = c;
#pragma unroll
  for (int ofs = 1; ofs < 64; ofs <<= 1) {
    int v = __shfl_up(inc, ofs);
    if (lane >= ofs) inc += v;
  }
  if (lane == 63) wsum[wid] = inc;
  __syncthreads();
  int pre = 0;
#pragma unroll
  for (int w = 0; w < 4; ++w) pre += (w < wid) ? wsum[w] : 0;
  int excl = inc + pre - c;
  if ((tid >> 4) == chunk) {
    s_excl[tid & 15] = excl;
    s_cnt[tid & 15] = c;
  }
  if (chunk == 0 && tid == 255) n_tot[e] = inc + pre;
  __syncthreads();
  int rbl = tid >> 4, i = tid & 15;
  int rb = chunk * 16 + rbl;
  if (i < s_cnt[rbl]) {
    int src = e * (RB_NUM * 16) + rb * 16 + i;
    int dst = e * N_TOK + s_excl[rbl] + i;
    dense_tok[dst] = tok_bkt[src];
    dense_p[dst] = p_bkt[src];
  }
}

// ---------- grouped gate/up GEMM (256 tok x 64 h tile, G+U fused) ----------
// round-0 proven structure: single-buffered LDS, 2 barriers/K-step, 3 blocks/CU.
// metadata from precomputed dense list. NOTE (r8/r9): both A and B MUST go
// through the coalesced llds16 staging path; per-lane direct-global fragment
// reads thrash L2 and amplify the scattered act stores 10-16x.
__global__ void __launch_bounds__(256, 2) moe_gateup_kernel(
    const short* __restrict__ xb, const short* __restrict__ wg,
    const short* __restrict__ wu, const int* __restrict__ dense_tok,
    const float* __restrict__ dense_p, const int* __restrict__ n_tot,
    const float* __restrict__ psum_blk, short* __restrict__ act,
    float* __restrict__ out_loss) {
  int e = blockIdx.z;
  int tid = threadIdx.x;

  if (e == 8) {  // load-balance loss
    if (blockIdx.x || blockIdx.y) return;
    __shared__ float sums[8];
    if (tid < 8) sums[tid] = 0.f;
    __syncthreads();
#pragma unroll
    for (int ee = 0; ee < 8; ++ee)
      atomicAdd(&sums[ee], psum_blk[tid * 8 + ee]);
    __syncthreads();
    if (tid == 0) {
      float lb = 0.f;
#pragma unroll
      for (int ee = 0; ee < 8; ++ee) {
        float pe = sums[ee] / (float)N_TOK;
        lb += pe * logf(pe * 8.f + 1e-10f);
      }
      out_loss[0] = 8.f * lb;
    }
    return;
  }

  int n_e = n_tot[e];
  int rt = blockIdx.y;
  if (rt * 256 >= n_e) return;  // uniform early exit, one scalar load
  int h0 = blockIdx.x * 64;

  __shared__ __align__(16) short As[256 * 64];   // 32 KB
  __shared__ __align__(16) short Bgs[64 * 64];   // 8 KB
  __shared__ __align__(16) short Bus[64 * 64];   // 8 KB
  __shared__ int s_row[256];
  __shared__ float s_pr[256];

  int lane = tid & 63, wid = tid >> 6;

  {
    int r = rt * 256 + tid;
    int srow = -1;
    float spr = 0.f;
    if (r < n_e) {
      srow = dense_tok[e * N_TOK + r];
      spr = dense_p[e * N_TOK + r];
    }
    s_row[tid] = srow;
    s_pr[tid] = spr;
  }
  __syncthreads();

  int cg = (lane & 7) ^ (lane >> 3);  // swizzled global chunk for this lane
  const short* baseA[8];
  const short* baseB[4];
#pragma unroll
  for (int jj = 0; jj < 8; ++jj) {
    int r = wid * 64 + jj * 8 + (lane >> 3);
    int row = s_row[r];
    int t = (row < 0) ? 0 : (row >> 1);
    baseA[jj] = xb + (size_t)t * D_DIM + cg * 8;
  }
  short* ldsB;
  {
    const short* wB = ((wid & 2) ? wu : wg) + (size_t)e * H_DIM * D_DIM;
    int rb = (wid & 1) * 32;
    ldsB = ((wid & 2) ? Bus : Bgs) + rb * 64;
#pragma unroll
    for (int jj = 0; jj < 4; ++jj) {
      int h = h0 + rb + jj * 8 + (lane >> 3);
      baseB[jj] = wB + (size_t)h * D_DIM + cg * 8;
    }
  }

  int ml = lane & 15, quad = lane >> 4;
  int m0w = wid * 64;
  f32x4 accG[4][4], accU[4][4];
#pragma unroll
  for (int mf = 0; mf < 4; ++mf)
#pragma unroll
    for (int nf = 0; nf < 4; ++nf) {
      accG[mf][nf] = (f32x4){0, 0, 0, 0};
      accU[mf][nf] = (f32x4){0, 0, 0, 0};
    }

  for (int kt = 0; kt < D_DIM / 64; ++kt) {
    int kb = kt * 64;
#pragma unroll
    for (int jj = 0; jj < 8; ++jj)
      llds16(baseA[jj] + kb, As + wid * 4096 + jj * 512);
#pragma unroll
    for (int jj = 0; jj < 4; ++jj)
      llds16(baseB[jj] + kb, ldsB + jj * 512);
    __syncthreads();
#pragma unroll
    for (int ks = 0; ks < 2; ++ks) {
      int cs = ((quad + ks * 4) ^ (ml & 7)) * 8;
      short8 a[4], bg[4], bu[4];
#pragma unroll
      for (int mf = 0; mf < 4; ++mf)
        a[mf] = *(const short8*)&As[(m0w + mf * 16 + ml) * 64 + cs];
#pragma unroll
      for (int nf = 0; nf < 4; ++nf) {
        bg[nf] = *(const short8*)&Bgs[(nf * 16 + ml) * 64 + cs];
        bu[nf] = *(const short8*)&Bus[(nf * 16 + ml) * 64 + cs];
      }
#pragma unroll
      for (int mf = 0; mf < 4; ++mf)
#pragma unroll
        for (int nf = 0; nf < 4; ++nf) {
          accG[mf][nf] = __builtin_amdgcn_mfma_f32_16x16x32_bf16(a[mf], bg[nf], accG[mf][nf], 0, 0, 0);
          accU[mf][nf] = __builtin_amdgcn_mfma_f32_16x16x32_bf16(a[mf], bu[nf], accU[mf][nf], 0, 0, 0);
        }
    }
    __syncthreads();
  }

#pragma unroll
  for (int mf = 0; mf < 4; ++mf)
#pragma unroll
    for (int r = 0; r < 4; ++r) {
      int rl = m0w + mf * 16 + quad * 4 + r;
      int arow = s_row[rl];
      if (arow >= 0) {
        float pr = s_pr[rl];
#pragma unroll
        for (int nf = 0; nf < 4; ++nf) {
          float g = accG[mf][nf][r], u = accU[mf][nf][r];
          float val = pr * (g / (1.f + __expf(-g))) * u;
          act[(size_t)arow * H_DIM + h0 + nf * 16 + ml] = f2bs(val);
        }
      }
    }
}

// ---------- down GEMM: partial[ksb][t][d] = act-slice @ wd ----------
// 64tok x 256d tile (act read only 2x total), Ksplit=4 over blockIdx.z.
// 4 waves: each owns 64tok x 64d strip; both slots accumulate into one acc
// with the B fragment reused in-register. 48 KB LDS -> 3 blocks/CU.
__global__ void __launch_bounds__(256, 3) down_kernel(
    const short* __restrict__ act, const short* __restrict__ wd,
    float* __restrict__ partial) {
  __shared__ __align__(16) short As0[64 * 64];   // 8 KB (slot 0)
  __shared__ __align__(16) short As1[64 * 64];   // 8 KB (slot 1)
  __shared__ __align__(16) short Bs[256 * 64];   // 32 KB
  int d0 = blockIdx.x * 256;
  int t0 = blockIdx.y * 64;
  int ksb = blockIdx.z;  // h-chunks [ksb*8, ksb*8+8)
  int tid = threadIdx.x, lane = tid & 63, wid = tid >> 6;
  int cg = (lane & 7) ^ (lane >> 3);

  const short* baseA[4];
  const short* baseB[8];
  int slot = wid >> 1;
  int arow0 = (wid & 1) * 32;
#pragma unroll
  for (int jj = 0; jj < 4; ++jj) {
    int r = arow0 + jj * 8 + (lane >> 3);
    baseA[jj] = act + (size_t)(2 * (t0 + r) + slot) * H_DIM + cg * 8;
  }
#pragma unroll
  for (int jj = 0; jj < 8; ++jj) {
    int d = d0 + wid * 64 + jj * 8 + (lane >> 3);
    baseB[jj] = wd + (size_t)d * H_DIM + cg * 8;
  }
  short* ldsA = (slot ? As1 : As0) + arow0 * 64;

  int ml = lane & 15, quad = lane >> 4;
  int n0w = wid * 64;
  f32x4 acc[4][4];
#pragma unroll
  for (int mf = 0; mf < 4; ++mf)
#pragma unroll
    for (int nf = 0; nf < 4; ++nf) acc[mf][nf] = (f32x4){0, 0, 0, 0};

  for (int j = 0; j < 8; ++j) {
    int hb = (ksb * 8 + j) * 64;
#pragma unroll
    for (int jj = 0; jj < 4; ++jj)
      llds16(baseA[jj] + hb, ldsA + jj * 512);
#pragma unroll
    for (int jj = 0; jj < 8; ++jj)
      llds16(baseB[jj] + hb, Bs + wid * 4096 + jj * 512);
    __syncthreads();
#pragma unroll
    for (int ks = 0; ks < 2; ++ks) {
      int cs = ((quad + ks * 4) ^ (ml & 7)) * 8;
      short8 a0[4], a1[4], b[4];
#pragma unroll
      for (int mf = 0; mf < 4; ++mf) {
        a0[mf] = *(const short8*)&As0[(mf * 16 + ml) * 64 + cs];
        a1[mf] = *(const short8*)&As1[(mf * 16 + ml) * 64 + cs];
      }
#pragma unroll
      for (int nf = 0; nf < 4; ++nf)
        b[nf] = *(const short8*)&Bs[(n0w + nf * 16 + ml) * 64 + cs];
#pragma unroll
      for (int mf = 0; mf < 4; ++mf)
#pragma unroll
        for (int nf = 0; nf < 4; ++nf) {
          acc[mf][nf] = __builtin_amdgcn_mfma_f32_16x16x32_bf16(a0[mf], b[nf], acc[mf][nf], 0, 0, 0);
          acc[mf][nf] = __builtin_amdgcn_mfma_f32_16x16x32_bf16(a1[mf], b[nf], acc[mf][nf], 0, 0, 0);
        }
    }
    __syncthreads();
  }

  float* pout = partial + (size_t)ksb * N_TOK * D_DIM;
#pragma unroll
  for (int mf = 0; mf < 4; ++mf)
#pragma unroll
    for (int r = 0; r < 4; ++r) {
      int t = t0 + mf * 16 + quad * 4 + r;
#pragma unroll
      for (int nf = 0; nf < 4; ++nf)
        pout[(size_t)t * D_DIM + d0 + n0w + nf * 16 + ml] = acc[mf][nf][r];
    }
}

// ---------- split-K reduce: out = sum of 4 partials ----------
__global__ void __launch_bounds__(256) reduce_kernel(
    const float* __restrict__ partial, float* __restrict__ out) {
  int i = blockIdx.x * 256 + threadIdx.x;  // float4 index
  const int Q = N_TOK * D_DIM / 4;
  const float4* p = (const float4*)partial;
  float4 a = p[i], b = p[i + Q], c = p[i + 2 * Q], d = p[i + 3 * Q];
  float4 r = {a.x + b.x + c.x + d.x, a.y + b.y + c.y + d.y,
              a.z + b.z + c.z + d.z, a.w + b.w + c.w + d.w};
  ((float4*)out)[i] = r;
}

extern "C" void kernel_launch(void* const* d_in, const int* in_sizes, int n_in,
                              void* d_out, int out_size, void* d_ws, size_t ws_size,
                              hipStream_t stream) {
  const float* x = (const float*)d_in[0];
  const float* wr = (const float*)d_in[1];
  const float* wg = (const float*)d_in[2];
  const float* wu = (const float*)d_in[3];
  const float* wd = (const float*)d_in[4];
  float* out = (float*)d_out;

  char* ws = (char*)d_ws;
  size_t off = 0;
  auto alloc = [&](size_t bytes) {
    char* p = ws + off;
    off += (bytes + 255) & ~(size_t)255;
    return p;
  };
  short* xb = (short*)alloc((size_t)N_TOK * D_DIM * 2);
  short* wgb = (short*)alloc((size_t)E_NUM * H_DIM * D_DIM * 2);  // [e*H+h][d]
  short* wub = (short*)alloc((size_t)E_NUM * H_DIM * D_DIM * 2);
  short* wdb = (short*)alloc((size_t)D_DIM * H_DIM * 2);          // [d][h]
  short* act = (short*)alloc((size_t)N_TOK * 2 * H_DIM * 2);      // [2t+slot][H]
  float* partial = (float*)alloc((size_t)4 * N_TOK * D_DIM * 4);  // split-K partials
  int* cnt_blk = (int*)alloc((size_t)RB_NUM * E_NUM * 4);
  int* tok_bkt = (int*)alloc((size_t)E_NUM * RB_NUM * 16 * 4);
  float* p_bkt = (float*)alloc((size_t)E_NUM * RB_NUM * 16 * 4);
  float* psum_blk = (float*)alloc((size_t)RB_NUM * E_NUM * 4);
  int* dense_tok = (int*)alloc((size_t)E_NUM * N_TOK * 4);
  float* dense_p = (float*)alloc((size_t)E_NUM * N_TOK * 4);
  int* n_tot = (int*)alloc((size_t)E_NUM * 4);

  prep_router_kernel<<<RB_NUM + TP_NUM, 256, 0, stream>>>(
      wg, wu, wd, x, wr, wgb, wub, wdb, xb, cnt_blk, tok_bkt, p_bkt, psum_blk);
  route_pack_kernel<<<E_NUM * 16, 256, 0, stream>>>(
      cnt_blk, tok_bkt, p_bkt, dense_tok, dense_p, n_tot);
  moe_gateup_kernel<<<dim3(H_DIM / 64, N_TOK / 256, E_NUM + 1), 256, 0, stream>>>(
      xb, wgb, wub, dense_tok, dense_p, n_tot, psum_blk, act,
      out + (size_t)N_TOK * D_DIM);
  down_kernel<<<dim3(D_DIM / 256, N_TOK / 64, 4), 256, 0, stream>>>(
      act, wdb, partial);
  reduce_kernel<<<N_TOK * D_DIM / 4 / 256, 256, 0, stream>>>(partial, out);
}

// Round 11
// 200.843 us; speedup vs baseline: 2.0135x; 1.0333x over previous
//
#include <hip/hip_runtime.h>
#include <hip/hip_bf16.h>

#define N_TOK 4096
#define D_DIM 512
#define E_NUM 8
#define H_DIM 2048
#define RB_NUM 256   // router blocks (16 tokens each)
#define TP_NUM 8704  // transpose tiles (64x32): 4096 wg + 4096 wu + 512 wd

typedef __attribute__((ext_vector_type(8))) short short8;
typedef __attribute__((ext_vector_type(4))) float f32x4;

__device__ inline short f2bs(float f) {
  __hip_bfloat16 h = __float2bfloat16(f);
  return *reinterpret_cast<short*>(&h);
}

// async global->LDS, 16 B per lane; lds dest is wave-uniform base + lane*16
__device__ inline void llds16(const short* g, short* l) {
  __builtin_amdgcn_global_load_lds(
      (const __attribute__((address_space(1))) void*)g,
      (__attribute__((address_space(3))) void*)l, 16, 0, 0);
}

// ---------- fused prep+router ----------
// blocks [0,256): router (16 tokens each, 16 lanes/token)
// blocks [256, 256+8704): 64r x 32c transpose tiles (wg/wu/wd)
// load phase: float4 (16 B/lane, 2 rounds); pack phase: round-0 proven scalar
__global__ void __launch_bounds__(256) prep_router_kernel(
    const float* __restrict__ wg, const float* __restrict__ wu,
    const float* __restrict__ wd, const float* __restrict__ x,
    const float* __restrict__ wr, short* __restrict__ wgb,
    short* __restrict__ wub, short* __restrict__ wdb, short* __restrict__ xb,
    int* __restrict__ cnt_blk, int* __restrict__ tok_bkt,
    float* __restrict__ p_bkt, float* __restrict__ psum_blk) {
  int u = blockIdx.x;
  int tid = threadIdx.x;

  if (u >= RB_NUM) {
    // ---- 64r x 32c transpose-convert, int-packed bf16 writes ----
    __shared__ float tbuf[64][33];
    int v = u - RB_NUM;
    const float* in;
    short* op;
    int R, C, c0, r0;
    if (v < 8192) {
      in = (v < 4096) ? wg : wu;
      op = (v < 4096) ? wgb : wub;
      int w = v & 4095;
      R = D_DIM; C = E_NUM * H_DIM;
      c0 = (w & 511) * 32; r0 = (w >> 9) * 64;
    } else {
      in = wd; op = wdb;
      int w = v - 8192;
      R = H_DIM; C = D_DIM;
      c0 = (w & 15) * 32; r0 = (w >> 4) * 64;
    }
    // load phase: float4 per lane; covers rows 0..63, cols 0..31
    int cx = tid & 7, ry = tid >> 3;  // cx: float4-col 0..7, ry: row 0..31
#pragma unroll
    for (int p = 0; p < 2; ++p) {
      int row = ry + 32 * p;
      float4 vv = *(const float4*)&in[(size_t)(r0 + row) * C + c0 + cx * 4];
      tbuf[row][cx * 4 + 0] = vv.x;
      tbuf[row][cx * 4 + 1] = vv.y;
      tbuf[row][cx * 4 + 2] = vv.z;
      tbuf[row][cx * 4 + 3] = vv.w;
    }
    __syncthreads();
    // pack phase: proven round-0 code (unchanged)
    int tx = tid & 31, ty = tid >> 5;
#pragma unroll
    for (int i = 0; i < 4; ++i) {
      int cl = ty + 8 * i;
      unsigned lo = (unsigned short)f2bs(tbuf[2 * tx][cl]);
      unsigned hi = (unsigned short)f2bs(tbuf[2 * tx + 1][cl]);
      ((int*)op)[(((size_t)(c0 + cl) * R) + r0) / 2 + tx] = (int)(lo | (hi << 16));
    }
    return;
  }

  // ---- router part: 16 tokens, 16 lanes per token ----
  __shared__ float wr_t[E_NUM * D_DIM];  // [e][d], 16 KB
  __shared__ int h_cnt[E_NUM];
  __shared__ float psh[E_NUM];
  int rb = u;
  for (int i = tid; i < D_DIM * E_NUM; i += 256)
    wr_t[(i & 7) * D_DIM + (i >> 3)] = wr[i];  // wr is [d][e]
  if (tid < E_NUM) { h_cnt[tid] = 0; psh[tid] = 0.f; }
  __syncthreads();

  int r = tid >> 4, pp = tid & 15;
  int t = rb * 16 + r;
  const float* xr0 = x + (size_t)t * D_DIM;
  short* xw0 = xb + (size_t)t * D_DIM;
  float acc[8] = {0, 0, 0, 0, 0, 0, 0, 0};
#pragma unroll
  for (int j = 0; j < 8; ++j) {
    int d = j * 64 + pp * 4;  // 16 lanes cover 64 consecutive floats
    float4 xv = *(const float4*)(xr0 + d);
    short4 o;
    o.x = f2bs(xv.x); o.y = f2bs(xv.y); o.z = f2bs(xv.z); o.w = f2bs(xv.w);
    *(short4*)(xw0 + d) = o;
#pragma unroll
    for (int e = 0; e < 8; ++e) {
      float4 w = *(const float4*)&wr_t[e * D_DIM + d];
      acc[e] += xv.x * w.x + xv.y * w.y + xv.z * w.z + xv.w * w.w;
    }
  }
#pragma unroll
  for (int e = 0; e < 8; ++e) {
    acc[e] += __shfl_xor(acc[e], 1);
    acc[e] += __shfl_xor(acc[e], 2);
    acc[e] += __shfl_xor(acc[e], 4);
    acc[e] += __shfl_xor(acc[e], 8);
  }

  if (pp == 0) {
    float m = acc[0];
#pragma unroll
    for (int e = 1; e < 8; ++e) m = fmaxf(m, acc[e]);
    float p[8], s = 0.f;
#pragma unroll
    for (int e = 0; e < 8; ++e) { p[e] = expf(acc[e] - m); s += p[e]; }
    float inv = 1.f / s;
#pragma unroll
    for (int e = 0; e < 8; ++e) {
      p[e] *= inv;
      atomicAdd(&psh[e], p[e]);  // LDS scope
    }
    int i0 = 0;
#pragma unroll
    for (int e = 1; e < 8; ++e) if (p[e] > p[i0]) i0 = e;
    int i1 = (i0 == 0) ? 1 : 0;
#pragma unroll
    for (int e = 0; e < 8; ++e) if (e != i0 && p[e] > p[i1]) i1 = e;
    float ps = p[i0] + p[i1] + 1e-10f;
    float q0 = p[i0] / ps, q1 = p[i1] / ps;
    int l0 = atomicAdd(&h_cnt[i0], 1);  // LDS scope
    int l1 = atomicAdd(&h_cnt[i1], 1);
    tok_bkt[i0 * (RB_NUM * 16) + rb * 16 + l0] = t * 2 + 0;
    p_bkt[i0 * (RB_NUM * 16) + rb * 16 + l0] = q0;
    tok_bkt[i1 * (RB_NUM * 16) + rb * 16 + l1] = t * 2 + 1;
    p_bkt[i1 * (RB_NUM * 16) + rb * 16 + l1] = q1;
  }
  __syncthreads();
  if (tid < E_NUM) {
    cnt_blk[rb * 8 + tid] = h_cnt[tid];   // plain stores, fully owned
    psum_blk[rb * 8 + tid] = psh[tid];
  }
}

// ---------- route pack: 128 blocks = 8 experts x 16 rb-chunks ----------
__global__ void __launch_bounds__(256) route_pack_kernel(
    const int* __restrict__ cnt_blk, const int* __restrict__ tok_bkt,
    const float* __restrict__ p_bkt, int* __restrict__ dense_tok,
    float* __restrict__ dense_p, int* __restrict__ n_tot) {
  int e = blockIdx.x >> 4;
  int chunk = blockIdx.x & 15;
  int tid = threadIdx.x, lane = tid & 63, wid = tid >> 6;
  __shared__ int wsum[4];
  __shared__ int s_excl[16];
  __shared__ int s_cnt[16];
  int c = cnt_blk[tid * 8 + e];
  int inc = c;
#pragma unroll
  for (int ofs = 1; ofs < 64; ofs <<= 1) {
    int v = __shfl_up(inc, ofs);
    if (lane >= ofs) inc += v;
  }
  if (lane == 63) wsum[wid] = inc;
  __syncthreads();
  int pre = 0;
#pragma unroll
  for (int w = 0; w < 4; ++w) pre += (w < wid) ? wsum[w] : 0;
  int excl = inc + pre - c;
  if ((tid >> 4) == chunk) {
    s_excl[tid & 15] = excl;
    s_cnt[tid & 15] = c;
  }
  if (chunk == 0 && tid == 255) n_tot[e] = inc + pre;
  __syncthreads();
  int rbl = tid >> 4, i = tid & 15;
  int rb = chunk * 16 + rbl;
  if (i < s_cnt[rbl]) {
    int src = e * (RB_NUM * 16) + rb * 16 + i;
    int dst = e * N_TOK + s_excl[rbl] + i;
    dense_tok[dst] = tok_bkt[src];
    dense_p[dst] = p_bkt[src];
  }
}

// ---------- grouped gate/up GEMM (256 tok x 64 h tile, G+U fused) ----------
// round-0 proven structure: single-buffered LDS, 2 barriers/K-step, 3 blocks/CU.
// metadata from precomputed dense list. NOTE (r8/r9): both A and B MUST go
// through the coalesced llds16 staging path; per-lane direct-global fragment
// reads thrash L2 and amplify the scattered act stores 10-16x.
__global__ void __launch_bounds__(256, 2) moe_gateup_kernel(
    const short* __restrict__ xb, const short* __restrict__ wg,
    const short* __restrict__ wu, const int* __restrict__ dense_tok,
    const float* __restrict__ dense_p, const int* __restrict__ n_tot,
    const float* __restrict__ psum_blk, short* __restrict__ act,
    float* __restrict__ out_loss) {
  int e = blockIdx.z;
  int tid = threadIdx.x;

  if (e == 8) {  // load-balance loss
    if (blockIdx.x || blockIdx.y) return;
    __shared__ float sums[8];
    if (tid < 8) sums[tid] = 0.f;
    __syncthreads();
#pragma unroll
    for (int ee = 0; ee < 8; ++ee)
      atomicAdd(&sums[ee], psum_blk[tid * 8 + ee]);
    __syncthreads();
    if (tid == 0) {
      float lb = 0.f;
#pragma unroll
      for (int ee = 0; ee < 8; ++ee) {
        float pe = sums[ee] / (float)N_TOK;
        lb += pe * logf(pe * 8.f + 1e-10f);
      }
      out_loss[0] = 8.f * lb;
    }
    return;
  }

  int n_e = n_tot[e];
  int rt = blockIdx.y;
  if (rt * 256 >= n_e) return;  // uniform early exit, one scalar load
  int h0 = blockIdx.x * 64;

  __shared__ __align__(16) short As[256 * 64];   // 32 KB
  __shared__ __align__(16) short Bgs[64 * 64];   // 8 KB
  __shared__ __align__(16) short Bus[64 * 64];   // 8 KB
  __shared__ int s_row[256];
  __shared__ float s_pr[256];

  int lane = tid & 63, wid = tid >> 6;

  {
    int r = rt * 256 + tid;
    int srow = -1;
    float spr = 0.f;
    if (r < n_e) {
      srow = dense_tok[e * N_TOK + r];
      spr = dense_p[e * N_TOK + r];
    }
    s_row[tid] = srow;
    s_pr[tid] = spr;
  }
  __syncthreads();

  int cg = (lane & 7) ^ (lane >> 3);  // swizzled global chunk for this lane
  const short* baseA[8];
  const short* baseB[4];
#pragma unroll
  for (int jj = 0; jj < 8; ++jj) {
    int r = wid * 64 + jj * 8 + (lane >> 3);
    int row = s_row[r];
    int t = (row < 0) ? 0 : (row >> 1);
    baseA[jj] = xb + (size_t)t * D_DIM + cg * 8;
  }
  short* ldsB;
  {
    const short* wB = ((wid & 2) ? wu : wg) + (size_t)e * H_DIM * D_DIM;
    int rb = (wid & 1) * 32;
    ldsB = ((wid & 2) ? Bus : Bgs) + rb * 64;
#pragma unroll
    for (int jj = 0; jj < 4; ++jj) {
      int h = h0 + rb + jj * 8 + (lane >> 3);
      baseB[jj] = wB + (size_t)h * D_DIM + cg * 8;
    }
  }

  int ml = lane & 15, quad = lane >> 4;
  int m0w = wid * 64;
  f32x4 accG[4][4], accU[4][4];
#pragma unroll
  for (int mf = 0; mf < 4; ++mf)
#pragma unroll
    for (int nf = 0; nf < 4; ++nf) {
      accG[mf][nf] = (f32x4){0, 0, 0, 0};
      accU[mf][nf] = (f32x4){0, 0, 0, 0};
    }

  for (int kt = 0; kt < D_DIM / 64; ++kt) {
    int kb = kt * 64;
#pragma unroll
    for (int jj = 0; jj < 8; ++jj)
      llds16(baseA[jj] + kb, As + wid * 4096 + jj * 512);
#pragma unroll
    for (int jj = 0; jj < 4; ++jj)
      llds16(baseB[jj] + kb, ldsB + jj * 512);
    __syncthreads();
#pragma unroll
    for (int ks = 0; ks < 2; ++ks) {
      int cs = ((quad + ks * 4) ^ (ml & 7)) * 8;
      short8 a[4], bg[4], bu[4];
#pragma unroll
      for (int mf = 0; mf < 4; ++mf)
        a[mf] = *(const short8*)&As[(m0w + mf * 16 + ml) * 64 + cs];
#pragma unroll
      for (int nf = 0; nf < 4; ++nf) {
        bg[nf] = *(const short8*)&Bgs[(nf * 16 + ml) * 64 + cs];
        bu[nf] = *(const short8*)&Bus[(nf * 16 + ml) * 64 + cs];
      }
#pragma unroll
      for (int mf = 0; mf < 4; ++mf)
#pragma unroll
        for (int nf = 0; nf < 4; ++nf) {
          accG[mf][nf] = __builtin_amdgcn_mfma_f32_16x16x32_bf16(a[mf], bg[nf], accG[mf][nf], 0, 0, 0);
          accU[mf][nf] = __builtin_amdgcn_mfma_f32_16x16x32_bf16(a[mf], bu[nf], accU[mf][nf], 0, 0, 0);
        }
    }
    __syncthreads();
  }

#pragma unroll
  for (int mf = 0; mf < 4; ++mf)
#pragma unroll
    for (int r = 0; r < 4; ++r) {
      int rl = m0w + mf * 16 + quad * 4 + r;
      int arow = s_row[rl];
      if (arow >= 0) {
        float pr = s_pr[rl];
#pragma unroll
        for (int nf = 0; nf < 4; ++nf) {
          float g = accG[mf][nf][r], u = accU[mf][nf][r];
          float val = pr * (g / (1.f + __expf(-g))) * u;
          act[(size_t)arow * H_DIM + h0 + nf * 16 + ml] = f2bs(val);
        }
      }
    }
}

// ---------- down GEMM: partial[ksb][t][d] = act-slice @ wd (bf16 partials) ----
// 64tok x 256d tile, Ksplit=4; flat grid 512 with XCD pair-swizzle: the two
// d-tiles (m=0,1) sharing one act slice get ids differing by 8 -> same XCD L2,
// issued in the same 16-block window -> second act read is an L2 hit.
__global__ void __launch_bounds__(256, 3) down_kernel(
    const short* __restrict__ act, const short* __restrict__ wd,
    short* __restrict__ partial) {
  // decode pair-swizzled flat id: 32 groups x 16 ids; ids r&7 and (r&7)+8
  // within a group are the two members of pair p = g*8 + (r&7).
  int bid = blockIdx.x;
  int g = bid >> 4, rr = bid & 15;
  int m = rr >> 3;             // pair member = d-tile
  int p = g * 8 + (rr & 7);    // pair = (ksb, tok-tile), 0..255
  int d0 = m * 256;
  int t0 = (p & 63) * 64;
  int ksb = p >> 6;            // h-chunks [ksb*8, ksb*8+8)

  __shared__ __align__(16) short As0[64 * 64];   // 8 KB (slot 0)
  __shared__ __align__(16) short As1[64 * 64];   // 8 KB (slot 1)
  __shared__ __align__(16) short Bs[256 * 64];   // 32 KB
  int tid = threadIdx.x, lane = tid & 63, wid = tid >> 6;
  int cg = (lane & 7) ^ (lane >> 3);

  const short* baseA[4];
  const short* baseB[8];
  int slot = wid >> 1;
  int arow0 = (wid & 1) * 32;
#pragma unroll
  for (int jj = 0; jj < 4; ++jj) {
    int r = arow0 + jj * 8 + (lane >> 3);
    baseA[jj] = act + (size_t)(2 * (t0 + r) + slot) * H_DIM + cg * 8;
  }
#pragma unroll
  for (int jj = 0; jj < 8; ++jj) {
    int d = d0 + wid * 64 + jj * 8 + (lane >> 3);
    baseB[jj] = wd + (size_t)d * H_DIM + cg * 8;
  }
  short* ldsA = (slot ? As1 : As0) + arow0 * 64;

  int ml = lane & 15, quad = lane >> 4;
  int n0w = wid * 64;
  f32x4 acc[4][4];
#pragma unroll
  for (int mf = 0; mf < 4; ++mf)
#pragma unroll
    for (int nf = 0; nf < 4; ++nf) acc[mf][nf] = (f32x4){0, 0, 0, 0};

  for (int j = 0; j < 8; ++j) {
    int hb = (ksb * 8 + j) * 64;
#pragma unroll
    for (int jj = 0; jj < 4; ++jj)
      llds16(baseA[jj] + hb, ldsA + jj * 512);
#pragma unroll
    for (int jj = 0; jj < 8; ++jj)
      llds16(baseB[jj] + hb, Bs + wid * 4096 + jj * 512);
    __syncthreads();
#pragma unroll
    for (int ks = 0; ks < 2; ++ks) {
      int cs = ((quad + ks * 4) ^ (ml & 7)) * 8;
      short8 a0[4], a1[4], b[4];
#pragma unroll
      for (int mf = 0; mf < 4; ++mf) {
        a0[mf] = *(const short8*)&As0[(mf * 16 + ml) * 64 + cs];
        a1[mf] = *(const short8*)&As1[(mf * 16 + ml) * 64 + cs];
      }
#pragma unroll
      for (int nf = 0; nf < 4; ++nf)
        b[nf] = *(const short8*)&Bs[(n0w + nf * 16 + ml) * 64 + cs];
#pragma unroll
      for (int mf = 0; mf < 4; ++mf)
#pragma unroll
        for (int nf = 0; nf < 4; ++nf) {
          acc[mf][nf] = __builtin_amdgcn_mfma_f32_16x16x32_bf16(a0[mf], b[nf], acc[mf][nf], 0, 0, 0);
          acc[mf][nf] = __builtin_amdgcn_mfma_f32_16x16x32_bf16(a1[mf], b[nf], acc[mf][nf], 0, 0, 0);
        }
    }
    __syncthreads();
  }

  short* pout = partial + (size_t)ksb * N_TOK * D_DIM;
#pragma unroll
  for (int mf = 0; mf < 4; ++mf)
#pragma unroll
    for (int r = 0; r < 4; ++r) {
      int t = t0 + mf * 16 + quad * 4 + r;
#pragma unroll
      for (int nf = 0; nf < 4; ++nf)
        pout[(size_t)t * D_DIM + d0 + n0w + nf * 16 + ml] = f2bs(acc[mf][nf][r]);
    }
}

// ---------- split-K reduce: out = sum of 4 bf16 partials ----------
__global__ void __launch_bounds__(256) reduce_kernel(
    const short* __restrict__ partial, float* __restrict__ out) {
  int i = blockIdx.x * 256 + threadIdx.x;  // short8 index (8 outputs/thread)
  const int Q = N_TOK * D_DIM / 8;
  float s[8];
#pragma unroll
  for (int j = 0; j < 8; ++j) s[j] = 0.f;
#pragma unroll
  for (int k = 0; k < 4; ++k) {
    short8 v = ((const short8*)partial)[i + k * Q];
#pragma unroll
    for (int j = 0; j < 8; ++j) {
      unsigned u = (unsigned)(unsigned short)v[j] << 16;
      s[j] += *reinterpret_cast<float*>(&u);
    }
  }
  float4 lo = {s[0], s[1], s[2], s[3]};
  float4 hi = {s[4], s[5], s[6], s[7]};
  ((float4*)out)[i * 2] = lo;
  ((float4*)out)[i * 2 + 1] = hi;
}

extern "C" void kernel_launch(void* const* d_in, const int* in_sizes, int n_in,
                              void* d_out, int out_size, void* d_ws, size_t ws_size,
                              hipStream_t stream) {
  const float* x = (const float*)d_in[0];
  const float* wr = (const float*)d_in[1];
  const float* wg = (const float*)d_in[2];
  const float* wu = (const float*)d_in[3];
  const float* wd = (const float*)d_in[4];
  float* out = (float*)d_out;

  char* ws = (char*)d_ws;
  size_t off = 0;
  auto alloc = [&](size_t bytes) {
    char* p = ws + off;
    off += (bytes + 255) & ~(size_t)255;
    return p;
  };
  short* xb = (short*)alloc((size_t)N_TOK * D_DIM * 2);
  short* wgb = (short*)alloc((size_t)E_NUM * H_DIM * D_DIM * 2);  // [e*H+h][d]
  short* wub = (short*)alloc((size_t)E_NUM * H_DIM * D_DIM * 2);
  short* wdb = (short*)alloc((size_t)D_DIM * H_DIM * 2);          // [d][h]
  short* act = (short*)alloc((size_t)N_TOK * 2 * H_DIM * 2);      // [2t+slot][H]
  short* partial = (short*)alloc((size_t)4 * N_TOK * D_DIM * 2);  // bf16 split-K partials
  int* cnt_blk = (int*)alloc((size_t)RB_NUM * E_NUM * 4);
  int* tok_bkt = (int*)alloc((size_t)E_NUM * RB_NUM * 16 * 4);
  float* p_bkt = (float*)alloc((size_t)E_NUM * RB_NUM * 16 * 4);
  float* psum_blk = (float*)alloc((size_t)RB_NUM * E_NUM * 4);
  int* dense_tok = (int*)alloc((size_t)E_NUM * N_TOK * 4);
  float* dense_p = (float*)alloc((size_t)E_NUM * N_TOK * 4);
  int* n_tot = (int*)alloc((size_t)E_NUM * 4);

  prep_router_kernel<<<RB_NUM + TP_NUM, 256, 0, stream>>>(
      wg, wu, wd, x, wr, wgb, wub, wdb, xb, cnt_blk, tok_bkt, p_bkt, psum_blk);
  route_pack_kernel<<<E_NUM * 16, 256, 0, stream>>>(
      cnt_blk, tok_bkt, p_bkt, dense_tok, dense_p, n_tot);
  moe_gateup_kernel<<<dim3(H_DIM / 64, N_TOK / 256, E_NUM + 1), 256, 0, stream>>>(
      xb, wgb, wub, dense_tok, dense_p, n_tot, psum_blk, act,
      out + (size_t)N_TOK * D_DIM);
  down_kernel<<<512, 256, 0, stream>>>(act, wdb, partial);
  reduce_kernel<<<N_TOK * D_DIM / 8 / 256, 256, 0, stream>>>(partial, out);
}

// Round 12
// 199.857 us; speedup vs baseline: 2.0235x; 1.0049x over previous
//
#include <hip/hip_runtime.h>
#include <hip/hip_bf16.h>

#define N_TOK 4096
#define D_DIM 512
#define E_NUM 8
#define H_DIM 2048
#define RB_NUM 256   // router blocks (16 tokens each)
#define TP_NUM 8704  // transpose tiles (64x32): 4096 wg + 4096 wu + 512 wd

typedef __attribute__((ext_vector_type(8))) short short8;
typedef __attribute__((ext_vector_type(4))) float f32x4;

__device__ inline short f2bs(float f) {
  __hip_bfloat16 h = __float2bfloat16(f);
  return *reinterpret_cast<short*>(&h);
}

// async global->LDS, 16 B per lane; lds dest is wave-uniform base + lane*16
__device__ inline void llds16(const short* g, short* l) {
  __builtin_amdgcn_global_load_lds(
      (const __attribute__((address_space(1))) void*)g,
      (__attribute__((address_space(3))) void*)l, 16, 0, 0);
}

// ---------- fused prep+router ----------
// blocks [0,256): router (16 tokens each, 16 lanes/token)
// blocks [256, 256+8704): 64r x 32c transpose tiles (wg/wu/wd)
// load phase: float4 (16 B/lane, 2 rounds); pack phase: round-0 proven scalar
__global__ void __launch_bounds__(256) prep_router_kernel(
    const float* __restrict__ wg, const float* __restrict__ wu,
    const float* __restrict__ wd, const float* __restrict__ x,
    const float* __restrict__ wr, short* __restrict__ wgb,
    short* __restrict__ wub, short* __restrict__ wdb, short* __restrict__ xb,
    int* __restrict__ cnt_blk, int* __restrict__ tok_bkt,
    float* __restrict__ p_bkt, float* __restrict__ psum_blk) {
  int u = blockIdx.x;
  int tid = threadIdx.x;

  if (u >= RB_NUM) {
    // ---- 64r x 32c transpose-convert, int-packed bf16 writes ----
    __shared__ float tbuf[64][33];
    int v = u - RB_NUM;
    const float* in;
    short* op;
    int R, C, c0, r0;
    if (v < 8192) {
      in = (v < 4096) ? wg : wu;
      op = (v < 4096) ? wgb : wub;
      int w = v & 4095;
      R = D_DIM; C = E_NUM * H_DIM;
      c0 = (w & 511) * 32; r0 = (w >> 9) * 64;
    } else {
      in = wd; op = wdb;
      int w = v - 8192;
      R = H_DIM; C = D_DIM;
      c0 = (w & 15) * 32; r0 = (w >> 4) * 64;
    }
    // load phase: float4 per lane; covers rows 0..63, cols 0..31
    int cx = tid & 7, ry = tid >> 3;  // cx: float4-col 0..7, ry: row 0..31
#pragma unroll
    for (int p = 0; p < 2; ++p) {
      int row = ry + 32 * p;
      float4 vv = *(const float4*)&in[(size_t)(r0 + row) * C + c0 + cx * 4];
      tbuf[row][cx * 4 + 0] = vv.x;
      tbuf[row][cx * 4 + 1] = vv.y;
      tbuf[row][cx * 4 + 2] = vv.z;
      tbuf[row][cx * 4 + 3] = vv.w;
    }
    __syncthreads();
    // pack phase: proven round-0 code (unchanged)
    int tx = tid & 31, ty = tid >> 5;
#pragma unroll
    for (int i = 0; i < 4; ++i) {
      int cl = ty + 8 * i;
      unsigned lo = (unsigned short)f2bs(tbuf[2 * tx][cl]);
      unsigned hi = (unsigned short)f2bs(tbuf[2 * tx + 1][cl]);
      ((int*)op)[(((size_t)(c0 + cl) * R) + r0) / 2 + tx] = (int)(lo | (hi << 16));
    }
    return;
  }

  // ---- router part: 16 tokens, 16 lanes per token ----
  __shared__ float wr_t[E_NUM * D_DIM];  // [e][d], 16 KB
  __shared__ int h_cnt[E_NUM];
  __shared__ float psh[E_NUM];
  int rb = u;
  for (int i = tid; i < D_DIM * E_NUM; i += 256)
    wr_t[(i & 7) * D_DIM + (i >> 3)] = wr[i];  // wr is [d][e]
  if (tid < E_NUM) { h_cnt[tid] = 0; psh[tid] = 0.f; }
  __syncthreads();

  int r = tid >> 4, pp = tid & 15;
  int t = rb * 16 + r;
  const float* xr0 = x + (size_t)t * D_DIM;
  short* xw0 = xb + (size_t)t * D_DIM;
  float acc[8] = {0, 0, 0, 0, 0, 0, 0, 0};
#pragma unroll
  for (int j = 0; j < 8; ++j) {
    int d = j * 64 + pp * 4;  // 16 lanes cover 64 consecutive floats
    float4 xv = *(const float4*)(xr0 + d);
    short4 o;
    o.x = f2bs(xv.x); o.y = f2bs(xv.y); o.z = f2bs(xv.z); o.w = f2bs(xv.w);
    *(short4*)(xw0 + d) = o;
#pragma unroll
    for (int e = 0; e < 8; ++e) {
      float4 w = *(const float4*)&wr_t[e * D_DIM + d];
      acc[e] += xv.x * w.x + xv.y * w.y + xv.z * w.z + xv.w * w.w;
    }
  }
#pragma unroll
  for (int e = 0; e < 8; ++e) {
    acc[e] += __shfl_xor(acc[e], 1);
    acc[e] += __shfl_xor(acc[e], 2);
    acc[e] += __shfl_xor(acc[e], 4);
    acc[e] += __shfl_xor(acc[e], 8);
  }

  if (pp == 0) {
    float m = acc[0];
#pragma unroll
    for (int e = 1; e < 8; ++e) m = fmaxf(m, acc[e]);
    float p[8], s = 0.f;
#pragma unroll
    for (int e = 0; e < 8; ++e) { p[e] = expf(acc[e] - m); s += p[e]; }
    float inv = 1.f / s;
#pragma unroll
    for (int e = 0; e < 8; ++e) {
      p[e] *= inv;
      atomicAdd(&psh[e], p[e]);  // LDS scope
    }
    int i0 = 0;
#pragma unroll
    for (int e = 1; e < 8; ++e) if (p[e] > p[i0]) i0 = e;
    int i1 = (i0 == 0) ? 1 : 0;
#pragma unroll
    for (int e = 0; e < 8; ++e) if (e != i0 && p[e] > p[i1]) i1 = e;
    float ps = p[i0] + p[i1] + 1e-10f;
    float q0 = p[i0] / ps, q1 = p[i1] / ps;
    int l0 = atomicAdd(&h_cnt[i0], 1);  // LDS scope
    int l1 = atomicAdd(&h_cnt[i1], 1);
    tok_bkt[i0 * (RB_NUM * 16) + rb * 16 + l0] = t * 2 + 0;
    p_bkt[i0 * (RB_NUM * 16) + rb * 16 + l0] = q0;
    tok_bkt[i1 * (RB_NUM * 16) + rb * 16 + l1] = t * 2 + 1;
    p_bkt[i1 * (RB_NUM * 16) + rb * 16 + l1] = q1;
  }
  __syncthreads();
  if (tid < E_NUM) {
    cnt_blk[rb * 8 + tid] = h_cnt[tid];   // plain stores, fully owned
    psum_blk[rb * 8 + tid] = psh[tid];
  }
}

// ---------- route pack: 128 blocks = 8 experts x 16 rb-chunks ----------
__global__ void __launch_bounds__(256) route_pack_kernel(
    const int* __restrict__ cnt_blk, const int* __restrict__ tok_bkt,
    const float* __restrict__ p_bkt, int* __restrict__ dense_tok,
    float* __restrict__ dense_p, int* __restrict__ n_tot) {
  int e = blockIdx.x >> 4;
  int chunk = blockIdx.x & 15;
  int tid = threadIdx.x, lane = tid & 63, wid = tid >> 6;
  __shared__ int wsum[4];
  __shared__ int s_excl[16];
  __shared__ int s_cnt[16];
  int c = cnt_blk[tid * 8 + e];
  int inc = c;
#pragma unroll
  for (int ofs = 1; ofs < 64; ofs <<= 1) {
    int v = __shfl_up(inc, ofs);
    if (lane >= ofs) inc += v;
  }
  if (lane == 63) wsum[wid] = inc;
  __syncthreads();
  int pre = 0;
#pragma unroll
  for (int w = 0; w < 4; ++w) pre += (w < wid) ? wsum[w] : 0;
  int excl = inc + pre - c;
  if ((tid >> 4) == chunk) {
    s_excl[tid & 15] = excl;
    s_cnt[tid & 15] = c;
  }
  if (chunk == 0 && tid == 255) n_tot[e] = inc + pre;
  __syncthreads();
  int rbl = tid >> 4, i = tid & 15;
  int rb = chunk * 16 + rbl;
  if (i < s_cnt[rbl]) {
    int src = e * (RB_NUM * 16) + rb * 16 + i;
    int dst = e * N_TOK + s_excl[rbl] + i;
    dense_tok[dst] = tok_bkt[src];
    dense_p[dst] = p_bkt[src];
  }
}

// ---------- grouped gate/up GEMM (256 tok x 64 h tile, G+U fused) ----------
// round-0 proven structure: single-buffered LDS, 2 barriers/K-step, 3 blocks/CU.
// metadata from precomputed dense list. NOTE (r8/r9): both A and B MUST go
// through the coalesced llds16 staging path; per-lane direct-global fragment
// reads thrash L2 and amplify the scattered act stores 10-16x.
__global__ void __launch_bounds__(256, 2) moe_gateup_kernel(
    const short* __restrict__ xb, const short* __restrict__ wg,
    const short* __restrict__ wu, const int* __restrict__ dense_tok,
    const float* __restrict__ dense_p, const int* __restrict__ n_tot,
    const float* __restrict__ psum_blk, short* __restrict__ act,
    float* __restrict__ out_loss) {
  int e = blockIdx.z;
  int tid = threadIdx.x;

  if (e == 8) {  // load-balance loss
    if (blockIdx.x || blockIdx.y) return;
    __shared__ float sums[8];
    if (tid < 8) sums[tid] = 0.f;
    __syncthreads();
#pragma unroll
    for (int ee = 0; ee < 8; ++ee)
      atomicAdd(&sums[ee], psum_blk[tid * 8 + ee]);
    __syncthreads();
    if (tid == 0) {
      float lb = 0.f;
#pragma unroll
      for (int ee = 0; ee < 8; ++ee) {
        float pe = sums[ee] / (float)N_TOK;
        lb += pe * logf(pe * 8.f + 1e-10f);
      }
      out_loss[0] = 8.f * lb;
    }
    return;
  }

  int n_e = n_tot[e];
  int rt = blockIdx.y;
  if (rt * 256 >= n_e) return;  // uniform early exit, one scalar load
  int h0 = blockIdx.x * 64;

  __shared__ __align__(16) short As[256 * 64];   // 32 KB
  __shared__ __align__(16) short Bgs[64 * 64];   // 8 KB
  __shared__ __align__(16) short Bus[64 * 64];   // 8 KB
  __shared__ int s_row[256];
  __shared__ float s_pr[256];

  int lane = tid & 63, wid = tid >> 6;

  {
    int r = rt * 256 + tid;
    int srow = -1;
    float spr = 0.f;
    if (r < n_e) {
      srow = dense_tok[e * N_TOK + r];
      spr = dense_p[e * N_TOK + r];
    }
    s_row[tid] = srow;
    s_pr[tid] = spr;
  }
  __syncthreads();

  int cg = (lane & 7) ^ (lane >> 3);  // swizzled global chunk for this lane
  const short* baseA[8];
  const short* baseB[4];
#pragma unroll
  for (int jj = 0; jj < 8; ++jj) {
    int r = wid * 64 + jj * 8 + (lane >> 3);
    int row = s_row[r];
    int t = (row < 0) ? 0 : (row >> 1);
    baseA[jj] = xb + (size_t)t * D_DIM + cg * 8;
  }
  short* ldsB;
  {
    const short* wB = ((wid & 2) ? wu : wg) + (size_t)e * H_DIM * D_DIM;
    int rb = (wid & 1) * 32;
    ldsB = ((wid & 2) ? Bus : Bgs) + rb * 64;
#pragma unroll
    for (int jj = 0; jj < 4; ++jj) {
      int h = h0 + rb + jj * 8 + (lane >> 3);
      baseB[jj] = wB + (size_t)h * D_DIM + cg * 8;
    }
  }

  int ml = lane & 15, quad = lane >> 4;
  int m0w = wid * 64;
  f32x4 accG[4][4], accU[4][4];
#pragma unroll
  for (int mf = 0; mf < 4; ++mf)
#pragma unroll
    for (int nf = 0; nf < 4; ++nf) {
      accG[mf][nf] = (f32x4){0, 0, 0, 0};
      accU[mf][nf] = (f32x4){0, 0, 0, 0};
    }

  for (int kt = 0; kt < D_DIM / 64; ++kt) {
    int kb = kt * 64;
#pragma unroll
    for (int jj = 0; jj < 8; ++jj)
      llds16(baseA[jj] + kb, As + wid * 4096 + jj * 512);
#pragma unroll
    for (int jj = 0; jj < 4; ++jj)
      llds16(baseB[jj] + kb, ldsB + jj * 512);
    __syncthreads();
#pragma unroll
    for (int ks = 0; ks < 2; ++ks) {
      int cs = ((quad + ks * 4) ^ (ml & 7)) * 8;
      short8 a[4], bg[4], bu[4];
#pragma unroll
      for (int mf = 0; mf < 4; ++mf)
        a[mf] = *(const short8*)&As[(m0w + mf * 16 + ml) * 64 + cs];
#pragma unroll
      for (int nf = 0; nf < 4; ++nf) {
        bg[nf] = *(const short8*)&Bgs[(nf * 16 + ml) * 64 + cs];
        bu[nf] = *(const short8*)&Bus[(nf * 16 + ml) * 64 + cs];
      }
#pragma unroll
      for (int mf = 0; mf < 4; ++mf)
#pragma unroll
        for (int nf = 0; nf < 4; ++nf) {
          accG[mf][nf] = __builtin_amdgcn_mfma_f32_16x16x32_bf16(a[mf], bg[nf], accG[mf][nf], 0, 0, 0);
          accU[mf][nf] = __builtin_amdgcn_mfma_f32_16x16x32_bf16(a[mf], bu[nf], accU[mf][nf], 0, 0, 0);
        }
    }
    __syncthreads();
  }

#pragma unroll
  for (int mf = 0; mf < 4; ++mf)
#pragma unroll
    for (int r = 0; r < 4; ++r) {
      int rl = m0w + mf * 16 + quad * 4 + r;
      int arow = s_row[rl];
      if (arow >= 0) {
        float pr = s_pr[rl];
#pragma unroll
        for (int nf = 0; nf < 4; ++nf) {
          float g = accG[mf][nf][r], u = accU[mf][nf][r];
          float val = pr * (g / (1.f + __expf(-g))) * u;
          act[(size_t)arow * H_DIM + h0 + nf * 16 + ml] = f2bs(val);
        }
      }
    }
}

// ---------- down GEMM: partial[ksb][t][d] = act-slice @ wd (bf16 partials) ----
// 64tok x 256d tile, Ksplit=4; flat grid 512 with XCD pair-swizzle. All blocks
// touching tok-tile tt (both d-tiles AND all 4 ksb-siblings) have id%8 == tt%8
// -> same XCD L2 under the round-robin heuristic; act re-read is an L2 hit.
__global__ void __launch_bounds__(256, 3) down_kernel(
    const short* __restrict__ act, const short* __restrict__ wd,
    short* __restrict__ partial) {
  // decode pair-swizzled flat id: 32 groups x 16 ids; ids r&7 and (r&7)+8
  // within a group are the two members of pair p = g*8 + (r&7).
  int bid = blockIdx.x;
  int g = bid >> 4, rr = bid & 15;
  int m = rr >> 3;             // pair member = d-tile
  int p = g * 8 + (rr & 7);    // pair = (ksb, tok-tile), 0..255
  int d0 = m * 256;
  int t0 = (p & 63) * 64;
  int ksb = p >> 6;            // h-chunks [ksb*8, ksb*8+8)

  __shared__ __align__(16) short As0[64 * 64];   // 8 KB (slot 0)
  __shared__ __align__(16) short As1[64 * 64];   // 8 KB (slot 1)
  __shared__ __align__(16) short Bs[256 * 64];   // 32 KB
  int tid = threadIdx.x, lane = tid & 63, wid = tid >> 6;
  int cg = (lane & 7) ^ (lane >> 3);

  const short* baseA[4];
  const short* baseB[8];
  int slot = wid >> 1;
  int arow0 = (wid & 1) * 32;
#pragma unroll
  for (int jj = 0; jj < 4; ++jj) {
    int r = arow0 + jj * 8 + (lane >> 3);
    baseA[jj] = act + (size_t)(2 * (t0 + r) + slot) * H_DIM + cg * 8;
  }
#pragma unroll
  for (int jj = 0; jj < 8; ++jj) {
    int d = d0 + wid * 64 + jj * 8 + (lane >> 3);
    baseB[jj] = wd + (size_t)d * H_DIM + cg * 8;
  }
  short* ldsA = (slot ? As1 : As0) + arow0 * 64;

  int ml = lane & 15, quad = lane >> 4;
  int n0w = wid * 64;
  f32x4 acc[4][4];
#pragma unroll
  for (int mf = 0; mf < 4; ++mf)
#pragma unroll
    for (int nf = 0; nf < 4; ++nf) acc[mf][nf] = (f32x4){0, 0, 0, 0};

  for (int j = 0; j < 8; ++j) {
    int hb = (ksb * 8 + j) * 64;
#pragma unroll
    for (int jj = 0; jj < 4; ++jj)
      llds16(baseA[jj] + hb, ldsA + jj * 512);
#pragma unroll
    for (int jj = 0; jj < 8; ++jj)
      llds16(baseB[jj] + hb, Bs + wid * 4096 + jj * 512);
    __syncthreads();
#pragma unroll
    for (int ks = 0; ks < 2; ++ks) {
      int cs = ((quad + ks * 4) ^ (ml & 7)) * 8;
      short8 a0[4], a1[4], b[4];
#pragma unroll
      for (int mf = 0; mf < 4; ++mf) {
        a0[mf] = *(const short8*)&As0[(mf * 16 + ml) * 64 + cs];
        a1[mf] = *(const short8*)&As1[(mf * 16 + ml) * 64 + cs];
      }
#pragma unroll
      for (int nf = 0; nf < 4; ++nf)
        b[nf] = *(const short8*)&Bs[(n0w + nf * 16 + ml) * 64 + cs];
#pragma unroll
      for (int mf = 0; mf < 4; ++mf)
#pragma unroll
        for (int nf = 0; nf < 4; ++nf) {
          acc[mf][nf] = __builtin_amdgcn_mfma_f32_16x16x32_bf16(a0[mf], b[nf], acc[mf][nf], 0, 0, 0);
          acc[mf][nf] = __builtin_amdgcn_mfma_f32_16x16x32_bf16(a1[mf], b[nf], acc[mf][nf], 0, 0, 0);
        }
    }
    __syncthreads();
  }

  short* pout = partial + (size_t)ksb * N_TOK * D_DIM;
#pragma unroll
  for (int mf = 0; mf < 4; ++mf)
#pragma unroll
    for (int r = 0; r < 4; ++r) {
      int t = t0 + mf * 16 + quad * 4 + r;
#pragma unroll
      for (int nf = 0; nf < 4; ++nf)
        pout[(size_t)t * D_DIM + d0 + n0w + nf * 16 + ml] = f2bs(acc[mf][nf][r]);
    }
}

// ---------- split-K reduce: out = sum of 4 bf16 partials ----------
// XCD-aligned decode: token-block a covers t = a*4..a*4+3, tok-tile tt = a/16.
// All down producers for tt sit on XCD tt%8, so pin this consumer to
// bid%8 == tt%8 via the bijection a = q*128 + (bid&7)*16 + s. Partials are
// then read from the producing XCD's L2 instead of cross-XCD HBM.
__global__ void __launch_bounds__(256) reduce_kernel(
    const short* __restrict__ partial, float* __restrict__ out) {
  int bid = blockIdx.x;
  int s0 = (bid >> 3) & 15, q = bid >> 7;
  int a = q * 128 + (bid & 7) * 16 + s0;
  int i = a * 256 + threadIdx.x;  // short8 index (8 outputs/thread)
  const int Q = N_TOK * D_DIM / 8;
  float s[8];
#pragma unroll
  for (int j = 0; j < 8; ++j) s[j] = 0.f;
#pragma unroll
  for (int k = 0; k < 4; ++k) {
    short8 v = ((const short8*)partial)[i + k * Q];
#pragma unroll
    for (int j = 0; j < 8; ++j) {
      unsigned u = (unsigned)(unsigned short)v[j] << 16;
      s[j] += *reinterpret_cast<float*>(&u);
    }
  }
  float4 lo = {s[0], s[1], s[2], s[3]};
  float4 hi = {s[4], s[5], s[6], s[7]};
  ((float4*)out)[i * 2] = lo;
  ((float4*)out)[i * 2 + 1] = hi;
}

extern "C" void kernel_launch(void* const* d_in, const int* in_sizes, int n_in,
                              void* d_out, int out_size, void* d_ws, size_t ws_size,
                              hipStream_t stream) {
  const float* x = (const float*)d_in[0];
  const float* wr = (const float*)d_in[1];
  const float* wg = (const float*)d_in[2];
  const float* wu = (const float*)d_in[3];
  const float* wd = (const float*)d_in[4];
  float* out = (float*)d_out;

  char* ws = (char*)d_ws;
  size_t off = 0;
  auto alloc = [&](size_t bytes) {
    char* p = ws + off;
    off += (bytes + 255) & ~(size_t)255;
    return p;
  };
  short* xb = (short*)alloc((size_t)N_TOK * D_DIM * 2);
  short* wgb = (short*)alloc((size_t)E_NUM * H_DIM * D_DIM * 2);  // [e*H+h][d]
  short* wub = (short*)alloc((size_t)E_NUM * H_DIM * D_DIM * 2);
  short* wdb = (short*)alloc((size_t)D_DIM * H_DIM * 2);          // [d][h]
  short* act = (short*)alloc((size_t)N_TOK * 2 * H_DIM * 2);      // [2t+slot][H]
  short* partial = (short*)alloc((size_t)4 * N_TOK * D_DIM * 2);  // bf16 split-K partials
  int* cnt_blk = (int*)alloc((size_t)RB_NUM * E_NUM * 4);
  int* tok_bkt = (int*)alloc((size_t)E_NUM * RB_NUM * 16 * 4);
  float* p_bkt = (float*)alloc((size_t)E_NUM * RB_NUM * 16 * 4);
  float* psum_blk = (float*)alloc((size_t)RB_NUM * E_NUM * 4);
  int* dense_tok = (int*)alloc((size_t)E_NUM * N_TOK * 4);
  float* dense_p = (float*)alloc((size_t)E_NUM * N_TOK * 4);
  int* n_tot = (int*)alloc((size_t)E_NUM * 4);

  prep_router_kernel<<<RB_NUM + TP_NUM, 256, 0, stream>>>(
      wg, wu, wd, x, wr, wgb, wub, wdb, xb, cnt_blk, tok_bkt, p_bkt, psum_blk);
  route_pack_kernel<<<E_NUM * 16, 256, 0, stream>>>(
      cnt_blk, tok_bkt, p_bkt, dense_tok, dense_p, n_tot);
  moe_gateup_kernel<<<dim3(H_DIM / 64, N_TOK / 256, E_NUM + 1), 256, 0, stream>>>(
      xb, wgb, wub, dense_tok, dense_p, n_tot, psum_blk, act,
      out + (size_t)N_TOK * D_DIM);
  down_kernel<<<512, 256, 0, stream>>>(act, wdb, partial);
  reduce_kernel<<<N_TOK * D_DIM / 8 / 256, 256, 0, stream>>>(partial, out);
}